// Round 1
// baseline (2889.221 us; speedup 1.0000x reference)
//
#include <hip/hip_runtime.h>

#define N_NODES 100000
#define N_EDGES 3200000
#define IN_DIM  62
#define OUT_DIM 16

// ---------------- K1: per-node projection + init ----------------
// z = h @ W_fc.T   (N x 16)
// a_src[i] = z[i] . W_attn[0:16],  a_dst[i] = z[i] . W_attn[16:32]
// also zero-inits denom[] and out[] (harness poisons them with 0xAA)
__global__ __launch_bounds__(256) void node_proj_kernel(
    const float* __restrict__ h,
    const float* __restrict__ W_fc,
    const float* __restrict__ W_attn,
    float* __restrict__ z,
    float* __restrict__ a_src_arr,
    float* __restrict__ a_dst_arr,
    float* __restrict__ denom,
    float* __restrict__ out)
{
    int i = blockIdx.x * blockDim.x + threadIdx.x;
    if (i >= N_NODES) return;

    float acc[OUT_DIM];
#pragma unroll
    for (int j = 0; j < OUT_DIM; ++j) acc[j] = 0.f;

    // h row: 62 floats = 31 aligned float2 (row stride 248 B, 8B-aligned)
    const float2* __restrict__ hr = (const float2*)(h + (size_t)i * IN_DIM);
#pragma unroll
    for (int kk = 0; kk < IN_DIM / 2; ++kk) {
        float2 hv = hr[kk];
#pragma unroll
        for (int j = 0; j < OUT_DIM; ++j) {
            // uniform addresses -> compiler scalarizes into s_load broadcasts
            acc[j] += hv.x * W_fc[j * IN_DIM + 2 * kk]
                    + hv.y * W_fc[j * IN_DIM + 2 * kk + 1];
        }
    }

    float asrc = 0.f, adst = 0.f;
#pragma unroll
    for (int j = 0; j < OUT_DIM; ++j) {
        asrc += acc[j] * W_attn[j];
        adst += acc[j] * W_attn[OUT_DIM + j];
    }

    float4* __restrict__ zrow = (float4*)(z + (size_t)i * OUT_DIM);
    zrow[0] = make_float4(acc[0],  acc[1],  acc[2],  acc[3]);
    zrow[1] = make_float4(acc[4],  acc[5],  acc[6],  acc[7]);
    zrow[2] = make_float4(acc[8],  acc[9],  acc[10], acc[11]);
    zrow[3] = make_float4(acc[12], acc[13], acc[14], acc[15]);

    a_src_arr[i] = asrc;
    a_dst_arr[i] = adst;
    denom[i] = 0.f;

    float4 z4 = make_float4(0.f, 0.f, 0.f, 0.f);
    float4* __restrict__ orow = (float4*)(out + (size_t)i * OUT_DIM);
    orow[0] = z4; orow[1] = z4; orow[2] = z4; orow[3] = z4;
}

// ---------------- K2: single edge pass ----------------
// For each edge: ea = leaky_relu(a_src[s] + a_dst[d] + ex.Wa_e)
// w = exp(ea)  (max-subtraction skipped: normalization is a per-node ratio,
// exponent magnitude is bounded ~10 so fp32 exp is safe)
// atomically accumulate denom[d] += w and out[d][:] += w*(z[s][:] + ez[:])
__global__ __launch_bounds__(256) void edge_kernel(
    const float* __restrict__ e,
    const int*   __restrict__ src,
    const int*   __restrict__ dst,
    const float* __restrict__ W_attn,
    const float* __restrict__ W_edge,
    const float* __restrict__ W_e2n,
    const float* __restrict__ z,
    const float* __restrict__ a_src_arr,
    const float* __restrict__ a_dst_arr,
    float* __restrict__ denom,
    float* __restrict__ out)
{
    int eid = blockIdx.x * blockDim.x + threadIdx.x;
    if (eid >= N_EDGES) return;

    int s = src[eid];
    int d = dst[eid];

    float2 ev = ((const float2*)e)[eid];
    // ex = e @ W_edge.T ; W_edge row-major (2,2)
    float ex0 = ev.x * W_edge[0] + ev.y * W_edge[1];
    float ex1 = ev.x * W_edge[2] + ev.y * W_edge[3];

    float a = a_src_arr[s] + a_dst_arr[d]
            + ex0 * W_attn[2 * OUT_DIM] + ex1 * W_attn[2 * OUT_DIM + 1];
    float ea = (a > 0.f) ? a : 0.01f * a;   // leaky_relu(0.01)
    float w  = __expf(ea);

    unsafeAtomicAdd(denom + d, w);

    const float4* __restrict__ zrow = (const float4*)(z + (size_t)s * OUT_DIM);
    float4 z0 = zrow[0], z1 = zrow[1], z2 = zrow[2], z3 = zrow[3];

    float* __restrict__ orow = out + (size_t)d * OUT_DIM;
    float zs[OUT_DIM] = { z0.x, z0.y, z0.z, z0.w,
                          z1.x, z1.y, z1.z, z1.w,
                          z2.x, z2.y, z2.z, z2.w,
                          z3.x, z3.y, z3.z, z3.w };
#pragma unroll
    for (int j = 0; j < OUT_DIM; ++j) {
        float ez = ex0 * W_e2n[2 * j] + ex1 * W_e2n[2 * j + 1];
        unsafeAtomicAdd(orow + j, w * (zs[j] + ez));
    }
}

// ---------------- K3: normalize ----------------
__global__ __launch_bounds__(256) void normalize_kernel(
    float* __restrict__ out, const float* __restrict__ denom)
{
    int tid = blockIdx.x * blockDim.x + threadIdx.x;        // one float4 each
    const int total = N_NODES * OUT_DIM / 4;
    if (tid >= total) return;
    int n = tid >> 2;
    float dn = denom[n];
    float inv = (dn != 0.f) ? (1.f / dn) : 0.f;
    float4 v = ((float4*)out)[tid];
    v.x *= inv; v.y *= inv; v.z *= inv; v.w *= inv;
    ((float4*)out)[tid] = v;
}

extern "C" void kernel_launch(void* const* d_in, const int* in_sizes, int n_in,
                              void* d_out, int out_size, void* d_ws, size_t ws_size,
                              hipStream_t stream)
{
    const float* h      = (const float*)d_in[0];
    const float* e      = (const float*)d_in[1];
    const int*   src    = (const int*)  d_in[2];
    const int*   dst    = (const int*)  d_in[3];
    const float* W_fc   = (const float*)d_in[4];
    const float* W_attn = (const float*)d_in[5];
    const float* W_edge = (const float*)d_in[6];
    const float* W_e2n  = (const float*)d_in[7];
    float* out = (float*)d_out;

    // workspace layout (bytes): z | a_src | a_dst | denom
    char* ws = (char*)d_ws;
    float* z         = (float*)(ws);
    float* a_src_arr = (float*)(ws + (size_t)N_NODES * OUT_DIM * 4);                 // 6.4 MB
    float* a_dst_arr = (float*)(ws + (size_t)N_NODES * OUT_DIM * 4 + N_NODES * 4);
    float* denom     = (float*)(ws + (size_t)N_NODES * OUT_DIM * 4 + 2 * (size_t)N_NODES * 4);

    node_proj_kernel<<<(N_NODES + 255) / 256, 256, 0, stream>>>(
        h, W_fc, W_attn, z, a_src_arr, a_dst_arr, denom, out);

    edge_kernel<<<(N_EDGES + 255) / 256, 256, 0, stream>>>(
        e, src, dst, W_attn, W_edge, W_e2n, z, a_src_arr, a_dst_arr, denom, out);

    normalize_kernel<<<(N_NODES * OUT_DIM / 4 + 255) / 256, 256, 0, stream>>>(
        out, denom);
}

// Round 4
// 657.773 us; speedup vs baseline: 4.3924x; 4.3924x over previous
//
#include <hip/hip_runtime.h>

#define N_NODES 100000
#define N_EDGES 3200000
#define IN_DIM  62
#define OUT_DIM 16
#define SCAN_BLOCK_ELEMS 1024
#define NB1 ((N_NODES + SCAN_BLOCK_ELEMS - 1) / SCAN_BLOCK_ELEMS)   // 98

// ---------------- K_a: per-node projection + ALL zero-init (no memsets) ----
__global__ __launch_bounds__(256) void node_proj_kernel(
    const float* __restrict__ h,
    const float* __restrict__ W_fc,
    const float* __restrict__ W_attn,
    float* __restrict__ z,
    float* __restrict__ a_src_arr,
    float* __restrict__ a_dst_arr,
    float* __restrict__ denom,
    int*   __restrict__ cnt,
    int*   __restrict__ cursor,
    float* __restrict__ out)
{
    int i = blockIdx.x * blockDim.x + threadIdx.x;
    if (i >= N_NODES) return;

    float acc[OUT_DIM];
#pragma unroll
    for (int j = 0; j < OUT_DIM; ++j) acc[j] = 0.f;

    const float2* __restrict__ hr = (const float2*)(h + (size_t)i * IN_DIM);
#pragma unroll
    for (int kk = 0; kk < IN_DIM / 2; ++kk) {
        float2 hv = hr[kk];
#pragma unroll
        for (int j = 0; j < OUT_DIM; ++j) {
            acc[j] += hv.x * W_fc[j * IN_DIM + 2 * kk]
                    + hv.y * W_fc[j * IN_DIM + 2 * kk + 1];
        }
    }

    float asrc = 0.f, adst = 0.f;
#pragma unroll
    for (int j = 0; j < OUT_DIM; ++j) {
        asrc += acc[j] * W_attn[j];
        adst += acc[j] * W_attn[OUT_DIM + j];
    }

    float4* __restrict__ zrow = (float4*)(z + (size_t)i * OUT_DIM);
    zrow[0] = make_float4(acc[0],  acc[1],  acc[2],  acc[3]);
    zrow[1] = make_float4(acc[4],  acc[5],  acc[6],  acc[7]);
    zrow[2] = make_float4(acc[8],  acc[9],  acc[10], acc[11]);
    zrow[3] = make_float4(acc[12], acc[13], acc[14], acc[15]);

    a_src_arr[i] = asrc;
    a_dst_arr[i] = adst;
    denom[i]  = 0.f;
    cnt[i]    = 0;
    cursor[i] = 0;

    float4 z4 = make_float4(0.f, 0.f, 0.f, 0.f);
    float4* __restrict__ orow = (float4*)(out + (size_t)i * OUT_DIM);
    orow[0] = z4; orow[1] = z4; orow[2] = z4; orow[3] = z4;
}

// ================= CSR-lite path (eid-only records, ~21.6 MB ws) ==========

__global__ __launch_bounds__(256) void hist_kernel(
    const int* __restrict__ dst, int* __restrict__ cnt)
{
    int eid = blockIdx.x * blockDim.x + threadIdx.x;
    if (eid >= N_EDGES) return;
    atomicAdd(cnt + dst[eid], 1);
}

__global__ __launch_bounds__(256) void scan1_kernel(
    const int* __restrict__ cnt,
    int* __restrict__ local_scan,
    int* __restrict__ block_sums)
{
    __shared__ int lds[256];
    int tid = threadIdx.x;
    int idx = blockIdx.x * SCAN_BLOCK_ELEMS + tid * 4;

    int v0 = (idx + 0 < N_NODES) ? cnt[idx + 0] : 0;
    int v1 = (idx + 1 < N_NODES) ? cnt[idx + 1] : 0;
    int v2 = (idx + 2 < N_NODES) ? cnt[idx + 2] : 0;
    int v3 = (idx + 3 < N_NODES) ? cnt[idx + 3] : 0;
    int tsum = v0 + v1 + v2 + v3;

    lds[tid] = tsum;
    __syncthreads();
    for (int off = 1; off < 256; off <<= 1) {
        int t = (tid >= off) ? lds[tid - off] : 0;
        __syncthreads();
        lds[tid] += t;
        __syncthreads();
    }
    int incl = lds[tid];
    int excl = incl - tsum;

    if (idx + 0 < N_NODES) local_scan[idx + 0] = excl;
    if (idx + 1 < N_NODES) local_scan[idx + 1] = excl + v0;
    if (idx + 2 < N_NODES) local_scan[idx + 2] = excl + v0 + v1;
    if (idx + 3 < N_NODES) local_scan[idx + 3] = excl + v0 + v1 + v2;
    if (tid == 255) block_sums[blockIdx.x] = incl;
}

__global__ __launch_bounds__(128) void scan2_kernel(
    const int* __restrict__ block_sums, int* __restrict__ block_pref)
{
    __shared__ int lds[128];
    int tid = threadIdx.x;
    int v = (tid < NB1) ? block_sums[tid] : 0;
    lds[tid] = v;
    __syncthreads();
    for (int off = 1; off < 128; off <<= 1) {
        int t = (tid >= off) ? lds[tid - off] : 0;
        __syncthreads();
        lds[tid] += t;
        __syncthreads();
    }
    if (tid < NB1) block_pref[tid] = lds[tid] - v;   // exclusive
}

__global__ __launch_bounds__(256) void scan3_kernel(
    const int* __restrict__ local_scan,
    const int* __restrict__ block_pref,
    int* __restrict__ offsets)
{
    int i = blockIdx.x * blockDim.x + threadIdx.x;
    if (i < N_NODES) offsets[i] = local_scan[i] + block_pref[i / SCAN_BLOCK_ELEMS];
    if (i == N_NODES) offsets[N_NODES] = N_EDGES;
}

// bucket edge ids by dst (one int atomic + one 4B write per edge)
__global__ __launch_bounds__(256) void scatter_kernel(
    const int* __restrict__ dst,
    const int* __restrict__ offsets,
    int*       __restrict__ cursor,
    int*       __restrict__ csr_eids)
{
    int eid = blockIdx.x * blockDim.x + threadIdx.x;
    if (eid >= N_EDGES) return;
    int d = dst[eid];
    int pos = offsets[d] + atomicAdd(cursor + d, 1);
    csr_eids[pos] = eid;
}

// 16 lanes per node: recompute w per edge, atomic-free reduce, fused normalize
__global__ __launch_bounds__(256) void gather_kernel(
    const int*   __restrict__ csr_eids,
    const int*   __restrict__ offsets,
    const int*   __restrict__ src,
    const float* __restrict__ e,
    const float* __restrict__ W_attn,
    const float* __restrict__ W_edge,
    const float* __restrict__ W_e2n,
    const float* __restrict__ z,
    const float* __restrict__ a_src_arr,
    const float* __restrict__ a_dst_arr,
    float* __restrict__ out)
{
    int node = blockIdx.x * 16 + (threadIdx.x >> 4);
    int lane = threadIdx.x & 15;
    if (node >= N_NODES) return;

    int beg = offsets[node];
    int end = offsets[node + 1];
    float adst = a_dst_arr[node];

    float acc = 0.f, accw = 0.f, accx0 = 0.f, accx1 = 0.f;
    for (int k = beg; k < end; ++k) {
        int eid = csr_eids[k];                       // sequential, group-broadcast
        int s   = src[eid];                          // random 4B, group-broadcast
        float2 ev = ((const float2*)e)[eid];         // random 8B, group-broadcast
        float ex0 = ev.x * W_edge[0] + ev.y * W_edge[1];
        float ex1 = ev.x * W_edge[2] + ev.y * W_edge[3];
        float a = a_src_arr[s] + adst
                + ex0 * W_attn[2 * OUT_DIM] + ex1 * W_attn[2 * OUT_DIM + 1];
        float ea = (a > 0.f) ? a : 0.01f * a;        // leaky_relu(0.01)
        float w  = __expf(ea);

        float zv = z[s * OUT_DIM + lane];            // coalesced 64B line
        acc   += w * zv;
        accw  += w;
        accx0 += w * ex0;
        accx1 += w * ex1;
    }

    float ez  = accx0 * W_e2n[2 * lane] + accx1 * W_e2n[2 * lane + 1];
    float inv = (accw != 0.f) ? (1.f / accw) : 0.f;
    out[(size_t)node * OUT_DIM + lane] = (acc + ez) * inv;
}

// ================= Fallback atomic path (round-1, known-passing) ==========

__global__ __launch_bounds__(256) void edge_kernel(
    const float* __restrict__ e,
    const int*   __restrict__ src,
    const int*   __restrict__ dst,
    const float* __restrict__ W_attn,
    const float* __restrict__ W_edge,
    const float* __restrict__ W_e2n,
    const float* __restrict__ z,
    const float* __restrict__ a_src_arr,
    const float* __restrict__ a_dst_arr,
    float* __restrict__ denom,
    float* __restrict__ out)
{
    int eid = blockIdx.x * blockDim.x + threadIdx.x;
    if (eid >= N_EDGES) return;

    int s = src[eid];
    int d = dst[eid];

    float2 ev = ((const float2*)e)[eid];
    float ex0 = ev.x * W_edge[0] + ev.y * W_edge[1];
    float ex1 = ev.x * W_edge[2] + ev.y * W_edge[3];

    float a = a_src_arr[s] + a_dst_arr[d]
            + ex0 * W_attn[2 * OUT_DIM] + ex1 * W_attn[2 * OUT_DIM + 1];
    float ea = (a > 0.f) ? a : 0.01f * a;
    float w  = __expf(ea);

    unsafeAtomicAdd(denom + d, w);

    const float4* __restrict__ zrow = (const float4*)(z + (size_t)s * OUT_DIM);
    float4 z0 = zrow[0], z1 = zrow[1], z2 = zrow[2], z3 = zrow[3];

    float* __restrict__ orow = out + (size_t)d * OUT_DIM;
    float zs[OUT_DIM] = { z0.x, z0.y, z0.z, z0.w,
                          z1.x, z1.y, z1.z, z1.w,
                          z2.x, z2.y, z2.z, z2.w,
                          z3.x, z3.y, z3.z, z3.w };
#pragma unroll
    for (int j = 0; j < OUT_DIM; ++j) {
        float ez = ex0 * W_e2n[2 * j] + ex1 * W_e2n[2 * j + 1];
        unsafeAtomicAdd(orow + j, w * (zs[j] + ez));
    }
}

__global__ __launch_bounds__(256) void normalize_kernel(
    float* __restrict__ out, const float* __restrict__ denom)
{
    int tid = blockIdx.x * blockDim.x + threadIdx.x;
    const int total = N_NODES * OUT_DIM / 4;
    if (tid >= total) return;
    int n = tid >> 2;
    float dn = denom[n];
    float inv = (dn != 0.f) ? (1.f / dn) : 0.f;
    float4 v = ((float4*)out)[tid];
    v.x *= inv; v.y *= inv; v.z *= inv; v.w *= inv;
    ((float4*)out)[tid] = v;
}

extern "C" void kernel_launch(void* const* d_in, const int* in_sizes, int n_in,
                              void* d_out, int out_size, void* d_ws, size_t ws_size,
                              hipStream_t stream)
{
    const float* h      = (const float*)d_in[0];
    const float* e      = (const float*)d_in[1];
    const int*   src    = (const int*)  d_in[2];
    const int*   dst    = (const int*)  d_in[3];
    const float* W_fc   = (const float*)d_in[4];
    const float* W_attn = (const float*)d_in[5];
    const float* W_edge = (const float*)d_in[6];
    const float* W_e2n  = (const float*)d_in[7];
    float* out = (float*)d_out;

    // ---- workspace layout ----
    char* ws = (char*)d_ws;
    size_t off = 0;
    float* z          = (float*)(ws + off); off += (size_t)N_NODES * OUT_DIM * 4;  // 6.4 MB
    float* a_src_arr  = (float*)(ws + off); off += (size_t)N_NODES * 4;
    float* a_dst_arr  = (float*)(ws + off); off += (size_t)N_NODES * 4;
    float* denom      = (float*)(ws + off); off += (size_t)N_NODES * 4;
    const size_t need_fallback = off;                                              // 7.6 MB
    int*   cnt        = (int*)  (ws + off); off += (size_t)N_NODES * 4;
    int*   cursor     = (int*)  (ws + off); off += (size_t)N_NODES * 4;
    int*   local_scan = (int*)  (ws + off); off += (size_t)N_NODES * 4;
    int*   offsets    = (int*)  (ws + off); off += (size_t)(N_NODES + 4) * 4;
    int*   block_sums = (int*)  (ws + off); off += 512;
    int*   block_pref = (int*)  (ws + off); off += 512;
    int*   csr_eids   = (int*)  (ws + off); off += (size_t)N_EDGES * 4;            // 12.8 MB
    const size_t need_csr = off;                                                   // ~21.6 MB
    (void)need_fallback;

    const bool use_csr = (ws_size >= need_csr);

    if (use_csr) {
        node_proj_kernel<<<(N_NODES + 255) / 256, 256, 0, stream>>>(
            h, W_fc, W_attn, z, a_src_arr, a_dst_arr, denom, cnt, cursor, out);

        hist_kernel<<<(N_EDGES + 255) / 256, 256, 0, stream>>>(dst, cnt);

        scan1_kernel<<<NB1, 256, 0, stream>>>(cnt, local_scan, block_sums);
        scan2_kernel<<<1, 128, 0, stream>>>(block_sums, block_pref);
        scan3_kernel<<<(N_NODES + 256) / 256, 256, 0, stream>>>(
            local_scan, block_pref, offsets);

        scatter_kernel<<<(N_EDGES + 255) / 256, 256, 0, stream>>>(
            dst, offsets, cursor, csr_eids);

        gather_kernel<<<(N_NODES + 15) / 16, 256, 0, stream>>>(
            csr_eids, offsets, src, e, W_attn, W_edge, W_e2n,
            z, a_src_arr, a_dst_arr, out);
    } else {
        // round-1 structure, proven on HW; cnt/cursor pointers may be past the
        // workspace end here, so node_proj gets denom for all three int inits
        node_proj_kernel<<<(N_NODES + 255) / 256, 256, 0, stream>>>(
            h, W_fc, W_attn, z, a_src_arr, a_dst_arr, denom,
            (int*)denom, (int*)denom, out);   // harmless re-zero of same region

        edge_kernel<<<(N_EDGES + 255) / 256, 256, 0, stream>>>(
            e, src, dst, W_attn, W_edge, W_e2n, z, a_src_arr, a_dst_arr, denom, out);

        normalize_kernel<<<(N_NODES * OUT_DIM / 4 + 255) / 256, 256, 0, stream>>>(
            out, denom);
    }
}

// Round 6
// 546.467 us; speedup vs baseline: 5.2871x; 1.2037x over previous
//
#include <hip/hip_runtime.h>

#define N_NODES 100000
#define N_EDGES 3200000
#define IN_DIM  62
#define OUT_DIM 16
#define SCAN_BLOCK_ELEMS 1024
#define NB1 ((N_NODES + SCAN_BLOCK_ELEMS - 1) / SCAN_BLOCK_ELEMS)   // 98

// ---------------- K_a: per-node projection + ALL zero-init (no memsets) ----
__global__ __launch_bounds__(256) void node_proj_kernel(
    const float* __restrict__ h,
    const float* __restrict__ W_fc,
    const float* __restrict__ W_attn,
    float* __restrict__ z,
    float* __restrict__ a_src_arr,
    float* __restrict__ a_dst_arr,
    float* __restrict__ denom,      // aliases cnt
    int*   __restrict__ cursor,
    float* __restrict__ out)
{
    int i = blockIdx.x * blockDim.x + threadIdx.x;
    if (i >= N_NODES) return;

    float acc[OUT_DIM];
#pragma unroll
    for (int j = 0; j < OUT_DIM; ++j) acc[j] = 0.f;

    const float2* __restrict__ hr = (const float2*)(h + (size_t)i * IN_DIM);
#pragma unroll
    for (int kk = 0; kk < IN_DIM / 2; ++kk) {
        float2 hv = hr[kk];
#pragma unroll
        for (int j = 0; j < OUT_DIM; ++j) {
            acc[j] += hv.x * W_fc[j * IN_DIM + 2 * kk]
                    + hv.y * W_fc[j * IN_DIM + 2 * kk + 1];
        }
    }

    float asrc = 0.f, adst = 0.f;
#pragma unroll
    for (int j = 0; j < OUT_DIM; ++j) {
        asrc += acc[j] * W_attn[j];
        adst += acc[j] * W_attn[OUT_DIM + j];
    }

    float4* __restrict__ zrow = (float4*)(z + (size_t)i * OUT_DIM);
    zrow[0] = make_float4(acc[0],  acc[1],  acc[2],  acc[3]);
    zrow[1] = make_float4(acc[4],  acc[5],  acc[6],  acc[7]);
    zrow[2] = make_float4(acc[8],  acc[9],  acc[10], acc[11]);
    zrow[3] = make_float4(acc[12], acc[13], acc[14], acc[15]);

    a_src_arr[i] = asrc;
    a_dst_arr[i] = adst;
    denom[i]  = 0.f;      // == cnt[i] = 0
    cursor[i] = 0;

    float4 z4 = make_float4(0.f, 0.f, 0.f, 0.f);
    float4* __restrict__ orow = (float4*)(out + (size_t)i * OUT_DIM);
    orow[0] = z4; orow[1] = z4; orow[2] = z4; orow[3] = z4;
}

// ================= histogram variants =================

// round-4 hist (tier B)
__global__ __launch_bounds__(256) void hist_kernel(
    const int* __restrict__ dst, int* __restrict__ cnt)
{
    int eid = blockIdx.x * blockDim.x + threadIdx.x;
    if (eid >= N_EDGES) return;
    atomicAdd(cnt + dst[eid], 1);
}

// hist + per-edge rank (tiers F, R): rank written sequentially
__global__ __launch_bounds__(256) void hist_rank_kernel(
    const int* __restrict__ dst, int* __restrict__ cnt,
    int* __restrict__ rank)
{
    int eid = blockIdx.x * blockDim.x + threadIdx.x;
    if (eid >= N_EDGES) return;
    rank[eid] = atomicAdd(cnt + dst[eid], 1);
}

// ================= prefix scan (unchanged) =================

__global__ __launch_bounds__(256) void scan1_kernel(
    const int* __restrict__ cnt,
    int* __restrict__ local_scan,
    int* __restrict__ block_sums)
{
    __shared__ int lds[256];
    int tid = threadIdx.x;
    int idx = blockIdx.x * SCAN_BLOCK_ELEMS + tid * 4;

    int v0 = (idx + 0 < N_NODES) ? cnt[idx + 0] : 0;
    int v1 = (idx + 1 < N_NODES) ? cnt[idx + 1] : 0;
    int v2 = (idx + 2 < N_NODES) ? cnt[idx + 2] : 0;
    int v3 = (idx + 3 < N_NODES) ? cnt[idx + 3] : 0;
    int tsum = v0 + v1 + v2 + v3;

    lds[tid] = tsum;
    __syncthreads();
    for (int off = 1; off < 256; off <<= 1) {
        int t = (tid >= off) ? lds[tid - off] : 0;
        __syncthreads();
        lds[tid] += t;
        __syncthreads();
    }
    int incl = lds[tid];
    int excl = incl - tsum;

    if (idx + 0 < N_NODES) local_scan[idx + 0] = excl;
    if (idx + 1 < N_NODES) local_scan[idx + 1] = excl + v0;
    if (idx + 2 < N_NODES) local_scan[idx + 2] = excl + v0 + v1;
    if (idx + 3 < N_NODES) local_scan[idx + 3] = excl + v0 + v1 + v2;
    if (tid == 255) block_sums[blockIdx.x] = incl;
}

__global__ __launch_bounds__(128) void scan2_kernel(
    const int* __restrict__ block_sums, int* __restrict__ block_pref)
{
    __shared__ int lds[128];
    int tid = threadIdx.x;
    int v = (tid < NB1) ? block_sums[tid] : 0;
    lds[tid] = v;
    __syncthreads();
    for (int off = 1; off < 128; off <<= 1) {
        int t = (tid >= off) ? lds[tid - off] : 0;
        __syncthreads();
        lds[tid] += t;
        __syncthreads();
    }
    if (tid < NB1) block_pref[tid] = lds[tid] - v;   // exclusive
}

__global__ __launch_bounds__(256) void scan3_kernel(
    const int* __restrict__ local_scan,
    const int* __restrict__ block_pref,
    int* __restrict__ offsets)
{
    int i = blockIdx.x * blockDim.x + threadIdx.x;
    if (i < N_NODES) offsets[i] = local_scan[i] + block_pref[i / SCAN_BLOCK_ELEMS];
    if (i == N_NODES) offsets[N_NODES] = N_EDGES;
}

// ================= scatter variants =================

// tier B: round-4 scatter (cursor atomics, eid records)
__global__ __launch_bounds__(256) void scatter_kernel(
    const int* __restrict__ dst,
    const int* __restrict__ offsets,
    int*       __restrict__ cursor,
    int*       __restrict__ csr_eids)
{
    int eid = blockIdx.x * blockDim.x + threadIdx.x;
    if (eid >= N_EDGES) return;
    int d = dst[eid];
    int pos = offsets[d] + atomicAdd(cursor + d, 1);
    csr_eids[pos] = eid;
}

// tier R: atomic-free scatter via precomputed rank, eid records
__global__ __launch_bounds__(256) void scatter_rank_kernel(
    const int* __restrict__ dst,
    const int* __restrict__ offsets,
    const int* __restrict__ rank,
    int*       __restrict__ csr_eids)
{
    int eid = blockIdx.x * blockDim.x + threadIdx.x;
    if (eid >= N_EDGES) return;
    int d = dst[eid];
    int pos = offsets[d] + rank[eid];
    csr_eids[pos] = eid;
}

// tier F: atomic-free scatter, fat 16B records {w, w*ex0, w*ex1, src}, nt stores
__global__ __launch_bounds__(256) void scatter_fat_kernel(
    const float* __restrict__ e,
    const int*   __restrict__ src,
    const int*   __restrict__ dst,
    const float* __restrict__ W_attn,
    const float* __restrict__ W_edge,
    const float* __restrict__ a_src_arr,
    const float* __restrict__ a_dst_arr,
    const int*   __restrict__ offsets,
    const int*   __restrict__ rank,
    float4*      __restrict__ records)
{
    int eid = blockIdx.x * blockDim.x + threadIdx.x;
    if (eid >= N_EDGES) return;

    int s = src[eid];
    int d = dst[eid];

    float2 ev = ((const float2*)e)[eid];
    float ex0 = ev.x * W_edge[0] + ev.y * W_edge[1];
    float ex1 = ev.x * W_edge[2] + ev.y * W_edge[3];

    float a = a_src_arr[s] + a_dst_arr[d]
            + ex0 * W_attn[2 * OUT_DIM] + ex1 * W_attn[2 * OUT_DIM + 1];
    float ea = (a > 0.f) ? a : 0.01f * a;          // leaky_relu(0.01)
    float w  = __expf(ea);

    int pos = offsets[d] + rank[eid];
    float* rp = (float*)(records + pos);
    __builtin_nontemporal_store(w,                   rp + 0);
    __builtin_nontemporal_store(w * ex0,             rp + 1);
    __builtin_nontemporal_store(w * ex1,             rp + 2);
    __builtin_nontemporal_store(__int_as_float(s),   rp + 3);
}

// ================= gather variants =================

// tiers B/R: eid records, recompute w (round-4 gather, proven)
__global__ __launch_bounds__(256) void gather_kernel(
    const int*   __restrict__ csr_eids,
    const int*   __restrict__ offsets,
    const int*   __restrict__ src,
    const float* __restrict__ e,
    const float* __restrict__ W_attn,
    const float* __restrict__ W_edge,
    const float* __restrict__ W_e2n,
    const float* __restrict__ z,
    const float* __restrict__ a_src_arr,
    const float* __restrict__ a_dst_arr,
    float* __restrict__ out)
{
    int node = blockIdx.x * 16 + (threadIdx.x >> 4);
    int lane = threadIdx.x & 15;
    if (node >= N_NODES) return;

    int beg = offsets[node];
    int end = offsets[node + 1];
    float adst = a_dst_arr[node];

    float acc = 0.f, accw = 0.f, accx0 = 0.f, accx1 = 0.f;
    for (int k = beg; k < end; ++k) {
        int eid = csr_eids[k];
        int s   = src[eid];
        float2 ev = ((const float2*)e)[eid];
        float ex0 = ev.x * W_edge[0] + ev.y * W_edge[1];
        float ex1 = ev.x * W_edge[2] + ev.y * W_edge[3];
        float a = a_src_arr[s] + adst
                + ex0 * W_attn[2 * OUT_DIM] + ex1 * W_attn[2 * OUT_DIM + 1];
        float ea = (a > 0.f) ? a : 0.01f * a;
        float w  = __expf(ea);

        float zv = z[s * OUT_DIM + lane];
        acc   += w * zv;
        accw  += w;
        accx0 += w * ex0;
        accx1 += w * ex1;
    }

    float ez  = accx0 * W_e2n[2 * lane] + accx1 * W_e2n[2 * lane + 1];
    float inv = (accw != 0.f) ? (1.f / accw) : 0.f;
    out[(size_t)node * OUT_DIM + lane] = (acc + ez) * inv;
}

// tier F: stream fat records (nt loads), only z is random
__global__ __launch_bounds__(256) void gather_fat_kernel(
    const float4* __restrict__ records,
    const int*    __restrict__ offsets,
    const float*  __restrict__ z,
    const float*  __restrict__ W_e2n,
    float* __restrict__ out)
{
    int node = blockIdx.x * 16 + (threadIdx.x >> 4);
    int lane = threadIdx.x & 15;
    if (node >= N_NODES) return;

    int beg = offsets[node];
    int end = offsets[node + 1];

    float acc = 0.f, accw = 0.f, accx0 = 0.f, accx1 = 0.f;
    const float* rp = (const float*)(records + beg);
    for (int k = beg; k < end; ++k, rp += 4) {
        float rw  = __builtin_nontemporal_load(rp + 0);
        float rx0 = __builtin_nontemporal_load(rp + 1);
        float rx1 = __builtin_nontemporal_load(rp + 2);
        float rs  = __builtin_nontemporal_load(rp + 3);
        int s = __float_as_int(rs);
        float zv = z[s * OUT_DIM + lane];            // coalesced 64B line
        acc   += rw * zv;
        accw  += rw;
        accx0 += rx0;
        accx1 += rx1;
    }

    float ez  = accx0 * W_e2n[2 * lane] + accx1 * W_e2n[2 * lane + 1];
    float inv = (accw != 0.f) ? (1.f / accw) : 0.f;
    out[(size_t)node * OUT_DIM + lane] = (acc + ez) * inv;
}

// ================= Fallback atomic path (round-1, known-passing) ==========

__global__ __launch_bounds__(256) void edge_kernel(
    const float* __restrict__ e,
    const int*   __restrict__ src,
    const int*   __restrict__ dst,
    const float* __restrict__ W_attn,
    const float* __restrict__ W_edge,
    const float* __restrict__ W_e2n,
    const float* __restrict__ z,
    const float* __restrict__ a_src_arr,
    const float* __restrict__ a_dst_arr,
    float* __restrict__ denom,
    float* __restrict__ out)
{
    int eid = blockIdx.x * blockDim.x + threadIdx.x;
    if (eid >= N_EDGES) return;

    int s = src[eid];
    int d = dst[eid];

    float2 ev = ((const float2*)e)[eid];
    float ex0 = ev.x * W_edge[0] + ev.y * W_edge[1];
    float ex1 = ev.x * W_edge[2] + ev.y * W_edge[3];

    float a = a_src_arr[s] + a_dst_arr[d]
            + ex0 * W_attn[2 * OUT_DIM] + ex1 * W_attn[2 * OUT_DIM + 1];
    float ea = (a > 0.f) ? a : 0.01f * a;
    float w  = __expf(ea);

    unsafeAtomicAdd(denom + d, w);

    const float4* __restrict__ zrow = (const float4*)(z + (size_t)s * OUT_DIM);
    float4 z0 = zrow[0], z1 = zrow[1], z2 = zrow[2], z3 = zrow[3];

    float* __restrict__ orow = out + (size_t)d * OUT_DIM;
    float zs[OUT_DIM] = { z0.x, z0.y, z0.z, z0.w,
                          z1.x, z1.y, z1.z, z1.w,
                          z2.x, z2.y, z2.z, z2.w,
                          z3.x, z3.y, z3.z, z3.w };
#pragma unroll
    for (int j = 0; j < OUT_DIM; ++j) {
        float ez = ex0 * W_e2n[2 * j] + ex1 * W_e2n[2 * j + 1];
        unsafeAtomicAdd(orow + j, w * (zs[j] + ez));
    }
}

__global__ __launch_bounds__(256) void normalize_kernel(
    float* __restrict__ out, const float* __restrict__ denom)
{
    int tid = blockIdx.x * blockDim.x + threadIdx.x;
    const int total = N_NODES * OUT_DIM / 4;
    if (tid >= total) return;
    int n = tid >> 2;
    float dn = denom[n];
    float inv = (dn != 0.f) ? (1.f / dn) : 0.f;
    float4 v = ((float4*)out)[tid];
    v.x *= inv; v.y *= inv; v.z *= inv; v.w *= inv;
    ((float4*)out)[tid] = v;
}

extern "C" void kernel_launch(void* const* d_in, const int* in_sizes, int n_in,
                              void* d_out, int out_size, void* d_ws, size_t ws_size,
                              hipStream_t stream)
{
    const float* h      = (const float*)d_in[0];
    const float* e      = (const float*)d_in[1];
    const int*   src    = (const int*)  d_in[2];
    const int*   dst    = (const int*)  d_in[3];
    const float* W_fc   = (const float*)d_in[4];
    const float* W_attn = (const float*)d_in[5];
    const float* W_edge = (const float*)d_in[6];
    const float* W_e2n  = (const float*)d_in[7];
    float* out = (float*)d_out;

    // ---- workspace layout (prefix identical to round-4's proven 21.6 MB) ----
    char* ws = (char*)d_ws;
    size_t off = 0;
    float* z          = (float*)(ws + off); off += (size_t)N_NODES * OUT_DIM * 4;
    float* a_src_arr  = (float*)(ws + off); off += (size_t)N_NODES * 4;
    float* a_dst_arr  = (float*)(ws + off); off += (size_t)N_NODES * 4;
    float* denom      = (float*)(ws + off);
    int*   cnt        = (int*)  (ws + off); off += (size_t)N_NODES * 4;   // denom ≡ cnt (different tiers)
    int*   cursor     = (int*)  (ws + off); off += (size_t)N_NODES * 4;
    int*   local_scan = (int*)  (ws + off); off += (size_t)N_NODES * 4;
    int*   offsets    = (int*)  (ws + off); off += (size_t)(N_NODES + 4) * 4;
    int*   block_sums = (int*)  (ws + off); off += 512;
    int*   block_pref = (int*)  (ws + off); off += 512;
    int*   slotA      = (int*)  (ws + off); off += (size_t)N_EDGES * 4;   // rank (F,R) | csr_eids (B)
    const size_t need_B = off;                                            // 21,601,040 B (proven fits)
    char*  slotB      = ws + off;                                         // csr_eids (R) | records (F)
    const size_t need_R = need_B + (size_t)N_EDGES * 4;                   // ~34.4 MB
    const size_t need_F = need_B + (size_t)N_EDGES * 16;                  // ~72.8 MB

    node_proj_kernel<<<(N_NODES + 255) / 256, 256, 0, stream>>>(
        h, W_fc, W_attn, z, a_src_arr, a_dst_arr, denom, cursor, out);

    const int EBLK = (N_EDGES + 255) / 256;
    const int NBLK = (N_NODES + 255) / 256;

    if (ws_size >= need_F) {
        // -------- tier F: rank hist + atomic-free fat scatter + streaming gather
        int* rank = slotA;
        float4* records = (float4*)slotB;

        hist_rank_kernel<<<EBLK, 256, 0, stream>>>(dst, cnt, rank);
        scan1_kernel<<<NB1, 256, 0, stream>>>(cnt, local_scan, block_sums);
        scan2_kernel<<<1, 128, 0, stream>>>(block_sums, block_pref);
        scan3_kernel<<<NBLK + 1, 256, 0, stream>>>(local_scan, block_pref, offsets);

        scatter_fat_kernel<<<EBLK, 256, 0, stream>>>(
            e, src, dst, W_attn, W_edge, a_src_arr, a_dst_arr, offsets, rank, records);

        gather_fat_kernel<<<(N_NODES + 15) / 16, 256, 0, stream>>>(
            records, offsets, z, W_e2n, out);
    } else if (ws_size >= need_R) {
        // -------- tier R: rank hist + atomic-free eid scatter + round-4 gather
        int* rank = slotA;
        int* csr_eids = (int*)slotB;

        hist_rank_kernel<<<EBLK, 256, 0, stream>>>(dst, cnt, rank);
        scan1_kernel<<<NB1, 256, 0, stream>>>(cnt, local_scan, block_sums);
        scan2_kernel<<<1, 128, 0, stream>>>(block_sums, block_pref);
        scan3_kernel<<<NBLK + 1, 256, 0, stream>>>(local_scan, block_pref, offsets);

        scatter_rank_kernel<<<EBLK, 256, 0, stream>>>(dst, offsets, rank, csr_eids);

        gather_kernel<<<(N_NODES + 15) / 16, 256, 0, stream>>>(
            csr_eids, offsets, src, e, W_attn, W_edge, W_e2n,
            z, a_src_arr, a_dst_arr, out);
    } else if (ws_size >= need_B) {
        // -------- tier B: exact round-4 path (proven 657 µs)
        int* csr_eids = slotA;

        hist_kernel<<<EBLK, 256, 0, stream>>>(dst, cnt);
        scan1_kernel<<<NB1, 256, 0, stream>>>(cnt, local_scan, block_sums);
        scan2_kernel<<<1, 128, 0, stream>>>(block_sums, block_pref);
        scan3_kernel<<<NBLK + 1, 256, 0, stream>>>(local_scan, block_pref, offsets);

        scatter_kernel<<<EBLK, 256, 0, stream>>>(dst, offsets, cursor, csr_eids);

        gather_kernel<<<(N_NODES + 15) / 16, 256, 0, stream>>>(
            csr_eids, offsets, src, e, W_attn, W_edge, W_e2n,
            z, a_src_arr, a_dst_arr, out);
    } else {
        // -------- round-1 atomic fallback
        edge_kernel<<<EBLK, 256, 0, stream>>>(
            e, src, dst, W_attn, W_edge, W_e2n, z, a_src_arr, a_dst_arr, denom, out);
        normalize_kernel<<<(N_NODES * OUT_DIM / 4 + 255) / 256, 256, 0, stream>>>(
            out, denom);
    }
}

// Round 8
// 468.469 us; speedup vs baseline: 6.1674x; 1.1665x over previous
//
#include <hip/hip_runtime.h>

#define N_NODES 100000
#define N_EDGES 3200000
#define IN_DIM  62
#define OUT_DIM 16
#define SCAN_BLOCK_ELEMS 1024
#define NB1 ((N_NODES + SCAN_BLOCK_ELEMS - 1) / SCAN_BLOCK_ELEMS)   // 98
#define NBLK ((N_NODES + 255) / 256)                                 // 391
#define EBLK (N_EDGES / 256)                                         // 12500
#define NCOPY 8

typedef float nat_f4 __attribute__((ext_vector_type(4)));   // builtin-legal float4

// ---------------- K0: zero the 8-copy histogram ----------------
__global__ __launch_bounds__(256) void zero_cnt8_kernel(int4* __restrict__ cnt8v)
{
    int i = blockIdx.x * blockDim.x + threadIdx.x;
    const int total = NCOPY * N_NODES / 4;              // 200000 int4
    if (i < total) cnt8v[i] = make_int4(0, 0, 0, 0);
}

// ---------------- K1: fused node projection + XCD-privatized hist+rank ----
// blocks [0, NBLK): node work; blocks [NBLK, NBLK+EBLK): edge histogram
__global__ __launch_bounds__(256) void fused_proj_hist_kernel(
    const float* __restrict__ h,
    const float* __restrict__ W_fc,
    const float* __restrict__ W_attn,
    const int*   __restrict__ dst,
    float* __restrict__ z,
    float* __restrict__ a_src_arr,
    float* __restrict__ a_dst_arr,
    int*   __restrict__ cnt8,
    unsigned short* __restrict__ rank)
{
    if (blockIdx.x < NBLK) {
        int i = blockIdx.x * 256 + threadIdx.x;
        if (i >= N_NODES) return;

        float acc[OUT_DIM];
#pragma unroll
        for (int j = 0; j < OUT_DIM; ++j) acc[j] = 0.f;

        const float2* __restrict__ hr = (const float2*)(h + (size_t)i * IN_DIM);
#pragma unroll
        for (int kk = 0; kk < IN_DIM / 2; ++kk) {
            float2 hv = hr[kk];
#pragma unroll
            for (int j = 0; j < OUT_DIM; ++j) {
                acc[j] += hv.x * W_fc[j * IN_DIM + 2 * kk]
                        + hv.y * W_fc[j * IN_DIM + 2 * kk + 1];
            }
        }

        float asrc = 0.f, adst = 0.f;
#pragma unroll
        for (int j = 0; j < OUT_DIM; ++j) {
            asrc += acc[j] * W_attn[j];
            adst += acc[j] * W_attn[OUT_DIM + j];
        }

        float4* __restrict__ zrow = (float4*)(z + (size_t)i * OUT_DIM);
        zrow[0] = make_float4(acc[0],  acc[1],  acc[2],  acc[3]);
        zrow[1] = make_float4(acc[4],  acc[5],  acc[6],  acc[7]);
        zrow[2] = make_float4(acc[8],  acc[9],  acc[10], acc[11]);
        zrow[3] = make_float4(acc[12], acc[13], acc[14], acc[15]);

        a_src_arr[i] = asrc;
        a_dst_arr[i] = adst;
    } else {
        int be  = blockIdx.x - NBLK;
        int eid = be * 256 + threadIdx.x;
        if (eid >= N_EDGES) return;
        int c = be & (NCOPY - 1);                       // XCD-local copy heuristic
        int d = dst[eid];
        int old = atomicAdd(cnt8 + c * N_NODES + d, 1);
        rank[eid] = (unsigned short)old;
    }
}

// ---------------- scan1x: fold 8 copies (in-place copy-prefix) + local scan
__global__ __launch_bounds__(256) void scan1x_kernel(
    int* __restrict__ cnt8,          // in: counts; out: per-copy exclusive prefix
    int* __restrict__ offsets,       // out: block-local exclusive scan of totals
    int* __restrict__ block_sums)
{
    __shared__ int lds[256];
    int tid = threadIdx.x;
    int idx = blockIdx.x * SCAN_BLOCK_ELEMS + tid * 4;

    int v[4];
#pragma unroll
    for (int u = 0; u < 4; ++u) {
        int d = idx + u;
        int tot = 0;
        if (d < N_NODES) {
            int pref = 0;
#pragma unroll
            for (int c = 0; c < NCOPY; ++c) {
                int cv = cnt8[c * N_NODES + d];
                cnt8[c * N_NODES + d] = pref;           // per-copy exclusive prefix
                pref += cv;
            }
            tot = pref;
        }
        v[u] = tot;
    }
    int tsum = v[0] + v[1] + v[2] + v[3];

    lds[tid] = tsum;
    __syncthreads();
    for (int off = 1; off < 256; off <<= 1) {
        int t = (tid >= off) ? lds[tid - off] : 0;
        __syncthreads();
        lds[tid] += t;
        __syncthreads();
    }
    int incl = lds[tid];
    int excl = incl - tsum;

    if (idx + 0 < N_NODES) offsets[idx + 0] = excl;
    if (idx + 1 < N_NODES) offsets[idx + 1] = excl + v[0];
    if (idx + 2 < N_NODES) offsets[idx + 2] = excl + v[0] + v[1];
    if (idx + 3 < N_NODES) offsets[idx + 3] = excl + v[0] + v[1] + v[2];
    if (tid == 255) block_sums[blockIdx.x] = incl;
}

__global__ __launch_bounds__(128) void scan2_kernel(
    const int* __restrict__ block_sums, int* __restrict__ block_pref)
{
    __shared__ int lds[128];
    int tid = threadIdx.x;
    int v = (tid < NB1) ? block_sums[tid] : 0;
    lds[tid] = v;
    __syncthreads();
    for (int off = 1; off < 128; off <<= 1) {
        int t = (tid >= off) ? lds[tid - off] : 0;
        __syncthreads();
        lds[tid] += t;
        __syncthreads();
    }
    if (tid < NB1) block_pref[tid] = lds[tid] - v;   // exclusive
}

// scan3x: offsets[i] += block_pref (in-place); sentinel at N_NODES
__global__ __launch_bounds__(256) void scan3x_kernel(
    const int* __restrict__ block_pref, int* __restrict__ offsets)
{
    int i = blockIdx.x * blockDim.x + threadIdx.x;
    if (i < N_NODES) offsets[i] += block_pref[i / SCAN_BLOCK_ELEMS];
    if (i == N_NODES) offsets[N_NODES] = N_EDGES;
}

// ---------------- scatter: atomic-free, fat 16B nt records ----------------
__global__ __launch_bounds__(256) void scatter_fat_kernel(
    const float* __restrict__ e,
    const int*   __restrict__ src,
    const int*   __restrict__ dst,
    const float* __restrict__ W_attn,
    const float* __restrict__ W_edge,
    const float* __restrict__ a_src_arr,
    const float* __restrict__ a_dst_arr,
    const int*   __restrict__ offsets,
    const int*   __restrict__ copy_pref,     // == cnt8 after scan1x
    const unsigned short* __restrict__ rank,
    float4*      __restrict__ records)
{
    int eid = blockIdx.x * blockDim.x + threadIdx.x;
    if (eid >= N_EDGES) return;

    int s = src[eid];
    int d = dst[eid];
    int c = (eid >> 8) & (NCOPY - 1);        // must match fused kernel's mapping

    float2 ev = ((const float2*)e)[eid];
    float ex0 = ev.x * W_edge[0] + ev.y * W_edge[1];
    float ex1 = ev.x * W_edge[2] + ev.y * W_edge[3];

    float a = a_src_arr[s] + a_dst_arr[d]
            + ex0 * W_attn[2 * OUT_DIM] + ex1 * W_attn[2 * OUT_DIM + 1];
    float ea = (a > 0.f) ? a : 0.01f * a;    // leaky_relu(0.01)
    float w  = __expf(ea);

    int pos = offsets[d] + copy_pref[c * N_NODES + d] + (int)rank[eid];
    float* rp = (float*)(records + pos);
    __builtin_nontemporal_store(w,                 rp + 0);
    __builtin_nontemporal_store(w * ex0,           rp + 1);
    __builtin_nontemporal_store(w * ex1,           rp + 2);
    __builtin_nontemporal_store(__int_as_float(s), rp + 3);
}

// ---------------- gather: stream records, unroll-2 dual accumulators ------
__global__ __launch_bounds__(256) void gather_fat_kernel(
    const float4* __restrict__ records,
    const int*    __restrict__ offsets,
    const float*  __restrict__ z,
    const float*  __restrict__ W_e2n,
    float* __restrict__ out)
{
    int node = blockIdx.x * 16 + (threadIdx.x >> 4);
    int lane = threadIdx.x & 15;
    if (node >= N_NODES) return;

    int beg = offsets[node];
    int end = offsets[node + 1];

    const nat_f4* __restrict__ rec = (const nat_f4*)records;

    float acc0 = 0.f, accw0 = 0.f, accx00 = 0.f, accx10 = 0.f;
    float acc1 = 0.f, accw1 = 0.f, accx01 = 0.f, accx11 = 0.f;

    int k = beg;
    for (; k + 1 < end; k += 2) {
        nat_f4 r0 = __builtin_nontemporal_load(rec + k);
        nat_f4 r1 = __builtin_nontemporal_load(rec + k + 1);
        int s0 = __float_as_int(r0.w);
        int s1 = __float_as_int(r1.w);
        float zv0 = z[s0 * OUT_DIM + lane];
        float zv1 = z[s1 * OUT_DIM + lane];
        acc0   += r0.x * zv0;   acc1   += r1.x * zv1;
        accw0  += r0.x;         accw1  += r1.x;
        accx00 += r0.y;         accx01 += r1.y;
        accx10 += r0.z;         accx11 += r1.z;
    }
    if (k < end) {
        nat_f4 r0 = __builtin_nontemporal_load(rec + k);
        int s0 = __float_as_int(r0.w);
        float zv0 = z[s0 * OUT_DIM + lane];
        acc0 += r0.x * zv0;  accw0 += r0.x;  accx00 += r0.y;  accx10 += r0.z;
    }

    float acc   = acc0 + acc1;
    float accw  = accw0 + accw1;
    float accx0 = accx00 + accx01;
    float accx1 = accx10 + accx11;

    float ez  = accx0 * W_e2n[2 * lane] + accx1 * W_e2n[2 * lane + 1];
    float inv = (accw != 0.f) ? (1.f / accw) : 0.f;
    out[(size_t)node * OUT_DIM + lane] = (acc + ez) * inv;
}

// ================= Fallback atomic path (round-1, known-passing) ==========

__global__ __launch_bounds__(256) void node_proj_fb_kernel(
    const float* __restrict__ h,
    const float* __restrict__ W_fc,
    const float* __restrict__ W_attn,
    float* __restrict__ z,
    float* __restrict__ a_src_arr,
    float* __restrict__ a_dst_arr,
    float* __restrict__ denom,
    float* __restrict__ out)
{
    int i = blockIdx.x * blockDim.x + threadIdx.x;
    if (i >= N_NODES) return;

    float acc[OUT_DIM];
#pragma unroll
    for (int j = 0; j < OUT_DIM; ++j) acc[j] = 0.f;

    const float2* __restrict__ hr = (const float2*)(h + (size_t)i * IN_DIM);
#pragma unroll
    for (int kk = 0; kk < IN_DIM / 2; ++kk) {
        float2 hv = hr[kk];
#pragma unroll
        for (int j = 0; j < OUT_DIM; ++j) {
            acc[j] += hv.x * W_fc[j * IN_DIM + 2 * kk]
                    + hv.y * W_fc[j * IN_DIM + 2 * kk + 1];
        }
    }

    float asrc = 0.f, adst = 0.f;
#pragma unroll
    for (int j = 0; j < OUT_DIM; ++j) {
        asrc += acc[j] * W_attn[j];
        adst += acc[j] * W_attn[OUT_DIM + j];
    }

    float4* __restrict__ zrow = (float4*)(z + (size_t)i * OUT_DIM);
    zrow[0] = make_float4(acc[0],  acc[1],  acc[2],  acc[3]);
    zrow[1] = make_float4(acc[4],  acc[5],  acc[6],  acc[7]);
    zrow[2] = make_float4(acc[8],  acc[9],  acc[10], acc[11]);
    zrow[3] = make_float4(acc[12], acc[13], acc[14], acc[15]);

    a_src_arr[i] = asrc;
    a_dst_arr[i] = adst;
    denom[i] = 0.f;

    float4 z4 = make_float4(0.f, 0.f, 0.f, 0.f);
    float4* __restrict__ orow = (float4*)(out + (size_t)i * OUT_DIM);
    orow[0] = z4; orow[1] = z4; orow[2] = z4; orow[3] = z4;
}

__global__ __launch_bounds__(256) void edge_kernel(
    const float* __restrict__ e,
    const int*   __restrict__ src,
    const int*   __restrict__ dst,
    const float* __restrict__ W_attn,
    const float* __restrict__ W_edge,
    const float* __restrict__ W_e2n,
    const float* __restrict__ z,
    const float* __restrict__ a_src_arr,
    const float* __restrict__ a_dst_arr,
    float* __restrict__ denom,
    float* __restrict__ out)
{
    int eid = blockIdx.x * blockDim.x + threadIdx.x;
    if (eid >= N_EDGES) return;

    int s = src[eid];
    int d = dst[eid];

    float2 ev = ((const float2*)e)[eid];
    float ex0 = ev.x * W_edge[0] + ev.y * W_edge[1];
    float ex1 = ev.x * W_edge[2] + ev.y * W_edge[3];

    float a = a_src_arr[s] + a_dst_arr[d]
            + ex0 * W_attn[2 * OUT_DIM] + ex1 * W_attn[2 * OUT_DIM + 1];
    float ea = (a > 0.f) ? a : 0.01f * a;
    float w  = __expf(ea);

    unsafeAtomicAdd(denom + d, w);

    const float4* __restrict__ zrow = (const float4*)(z + (size_t)s * OUT_DIM);
    float4 z0 = zrow[0], z1 = zrow[1], z2 = zrow[2], z3 = zrow[3];

    float* __restrict__ orow = out + (size_t)d * OUT_DIM;
    float zs[OUT_DIM] = { z0.x, z0.y, z0.z, z0.w,
                          z1.x, z1.y, z1.z, z1.w,
                          z2.x, z2.y, z2.z, z2.w,
                          z3.x, z3.y, z3.z, z3.w };
#pragma unroll
    for (int j = 0; j < OUT_DIM; ++j) {
        float ez = ex0 * W_e2n[2 * j] + ex1 * W_e2n[2 * j + 1];
        unsafeAtomicAdd(orow + j, w * (zs[j] + ez));
    }
}

__global__ __launch_bounds__(256) void normalize_kernel(
    float* __restrict__ out, const float* __restrict__ denom)
{
    int tid = blockIdx.x * blockDim.x + threadIdx.x;
    const int total = N_NODES * OUT_DIM / 4;
    if (tid >= total) return;
    int n = tid >> 2;
    float dn = denom[n];
    float inv = (dn != 0.f) ? (1.f / dn) : 0.f;
    float4 v = ((float4*)out)[tid];
    v.x *= inv; v.y *= inv; v.z *= inv; v.w *= inv;
    ((float4*)out)[tid] = v;
}

extern "C" void kernel_launch(void* const* d_in, const int* in_sizes, int n_in,
                              void* d_out, int out_size, void* d_ws, size_t ws_size,
                              hipStream_t stream)
{
    const float* h      = (const float*)d_in[0];
    const float* e      = (const float*)d_in[1];
    const int*   src    = (const int*)  d_in[2];
    const int*   dst    = (const int*)  d_in[3];
    const float* W_fc   = (const float*)d_in[4];
    const float* W_attn = (const float*)d_in[5];
    const float* W_edge = (const float*)d_in[6];
    const float* W_e2n  = (const float*)d_in[7];
    float* out = (float*)d_out;

    // ---- workspace layout (tier X: 68,401,040 B < proven 72.8 MB) ----
    char* ws = (char*)d_ws;
    size_t off = 0;
    float* z          = (float*)(ws + off); off += (size_t)N_NODES * OUT_DIM * 4;  // 6.4 MB
    float* a_src_arr  = (float*)(ws + off); off += (size_t)N_NODES * 4;
    float* a_dst_arr  = (float*)(ws + off); off += (size_t)N_NODES * 4;
    float* denom      = (float*)(ws + off);                          // fallback alias of cnt8
    int*   cnt8       = (int*)  (ws + off); off += (size_t)NCOPY * N_NODES * 4;    // 3.2 MB
    int*   offsets    = (int*)  (ws + off); off += (size_t)(N_NODES + 4) * 4;
    int*   block_sums = (int*)  (ws + off); off += 512;
    int*   block_pref = (int*)  (ws + off); off += 512;
    unsigned short* rank = (unsigned short*)(ws + off); off += (size_t)N_EDGES * 2; // 6.4 MB
    float4* records   = (float4*)(ws + off); off += (size_t)N_EDGES * 16;           // 51.2 MB
    const size_t need_X = off;   // 68,401,040

    if (ws_size >= need_X) {
        zero_cnt8_kernel<<<(NCOPY * N_NODES / 4 + 255) / 256, 256, 0, stream>>>(
            (int4*)cnt8);

        fused_proj_hist_kernel<<<NBLK + EBLK, 256, 0, stream>>>(
            h, W_fc, W_attn, dst, z, a_src_arr, a_dst_arr, cnt8, rank);

        scan1x_kernel<<<NB1, 256, 0, stream>>>(cnt8, offsets, block_sums);
        scan2_kernel<<<1, 128, 0, stream>>>(block_sums, block_pref);
        scan3x_kernel<<<NBLK + 1, 256, 0, stream>>>(block_pref, offsets);

        scatter_fat_kernel<<<EBLK, 256, 0, stream>>>(
            e, src, dst, W_attn, W_edge, a_src_arr, a_dst_arr,
            offsets, cnt8, rank, records);

        gather_fat_kernel<<<(N_NODES + 15) / 16, 256, 0, stream>>>(
            records, offsets, z, W_e2n, out);
    } else {
        // -------- round-1 atomic fallback (needs 7.6 MB) --------
        node_proj_fb_kernel<<<NBLK, 256, 0, stream>>>(
            h, W_fc, W_attn, z, a_src_arr, a_dst_arr, denom, out);

        edge_kernel<<<EBLK, 256, 0, stream>>>(
            e, src, dst, W_attn, W_edge, W_e2n, z, a_src_arr, a_dst_arr, denom, out);

        normalize_kernel<<<(N_NODES * OUT_DIM / 4 + 255) / 256, 256, 0, stream>>>(
            out, denom);
    }
}

// Round 9
// 461.455 us; speedup vs baseline: 6.2611x; 1.0152x over previous
//
#include <hip/hip_runtime.h>

#define N_NODES 100000
#define N_EDGES 3200000
#define IN_DIM  62
#define OUT_DIM 16
#define NBLK   ((N_NODES + 255) / 256)          // 391 node-proj blocks
#define EB_CHUNK 8192                            // edges per count/append block
#define NEB    ((N_EDGES + EB_CHUNK - 1) / EB_CHUNK)   // 391 edge blocks
#define NBUCK  ((N_NODES + 63) / 64)             // 1563 buckets (dst>>6)
#define NSEG   (NBUCK * 8)                       // 12504 (bucket,class) segments
#define CAP    3072                              // records/bucket LDS cap (avg 2048, +22 sigma)

typedef float nat_f4 __attribute__((ext_vector_type(4)));

// ---------------- K0: zero the (bucket,class) counters ----------------
__global__ __launch_bounds__(256) void zero_seg_kernel(int* __restrict__ cnt8b)
{
    int i = blockIdx.x * blockDim.x + threadIdx.x;
    if (i < NSEG) cnt8b[i] = 0;
}

// ---------------- K1: fused node projection + LDS-aggregated bucket count
// blocks [0,NBLK): node proj; blocks [NBLK, NBLK+NEB): edge count
__global__ __launch_bounds__(256) void fused_proj_count_kernel(
    const float* __restrict__ h,
    const float* __restrict__ W_fc,
    const float* __restrict__ W_attn,
    const int*   __restrict__ dst,
    float* __restrict__ z,
    float* __restrict__ a_src_arr,
    float* __restrict__ a_dst_arr,
    int*   __restrict__ cnt8b)
{
    __shared__ int cnt[NBUCK];                   // 6.25 KB

    if (blockIdx.x < NBLK) {
        int i = blockIdx.x * 256 + threadIdx.x;
        if (i >= N_NODES) return;

        float acc[OUT_DIM];
#pragma unroll
        for (int j = 0; j < OUT_DIM; ++j) acc[j] = 0.f;

        const float2* __restrict__ hr = (const float2*)(h + (size_t)i * IN_DIM);
#pragma unroll
        for (int kk = 0; kk < IN_DIM / 2; ++kk) {
            float2 hv = hr[kk];
#pragma unroll
            for (int j = 0; j < OUT_DIM; ++j) {
                acc[j] += hv.x * W_fc[j * IN_DIM + 2 * kk]
                        + hv.y * W_fc[j * IN_DIM + 2 * kk + 1];
            }
        }

        float asrc = 0.f, adst = 0.f;
#pragma unroll
        for (int j = 0; j < OUT_DIM; ++j) {
            asrc += acc[j] * W_attn[j];
            adst += acc[j] * W_attn[OUT_DIM + j];
        }

        float4* __restrict__ zrow = (float4*)(z + (size_t)i * OUT_DIM);
        zrow[0] = make_float4(acc[0],  acc[1],  acc[2],  acc[3]);
        zrow[1] = make_float4(acc[4],  acc[5],  acc[6],  acc[7]);
        zrow[2] = make_float4(acc[8],  acc[9],  acc[10], acc[11]);
        zrow[3] = make_float4(acc[12], acc[13], acc[14], acc[15]);

        a_src_arr[i] = asrc;
        a_dst_arr[i] = adst;
    } else {
        int be  = blockIdx.x - NBLK;             // edge-chunk index (must match K3)
        int cls = be & 7;
        int tid = threadIdx.x;
        long ebase = (long)be * EB_CHUNK;

        for (int t = tid; t < NBUCK; t += 256) cnt[t] = 0;
        __syncthreads();

        for (int j = 0; j < EB_CHUNK / 256; ++j) {
            long eid = ebase + j * 256 + tid;
            if (eid < N_EDGES) atomicAdd(&cnt[dst[eid] >> 6], 1);
        }
        __syncthreads();

        for (int t = tid; t < NBUCK; t += 256) {
            int v = cnt[t];
            if (v) atomicAdd(&cnt8b[t * 8 + cls], v);
        }
    }
}

// ---------------- K2: exclusive scan of 12504 segment counts (1 block) ----
__global__ __launch_bounds__(256) void scan_seg_kernel(
    const int* __restrict__ cnt8b,
    int* __restrict__ bases8,
    int* __restrict__ cursor8,
    int* __restrict__ offsets)
{
    __shared__ int sums[256];
    int tid = threadIdx.x;
    const int PER = (NSEG + 255) / 256;          // 49

    int s = 0;
    for (int k = 0; k < PER; ++k) {
        int i = tid * PER + k;
        if (i < NSEG) s += cnt8b[i];
    }
    sums[tid] = s;
    __syncthreads();
    for (int off = 1; off < 256; off <<= 1) {
        int t = (tid >= off) ? sums[tid - off] : 0;
        __syncthreads();
        sums[tid] += t;
        __syncthreads();
    }
    int run = sums[tid] - s;                     // exclusive base for this chunk
    for (int k = 0; k < PER; ++k) {
        int i = tid * PER + k;
        if (i < NSEG) {
            int v = cnt8b[i];
            bases8[i]  = run;
            cursor8[i] = run;
            run += v;
        }
    }
    if (tid == 0) {
        bases8[NSEG]      = N_EDGES;             // sentinel
        offsets[N_NODES]  = N_EDGES;             // gather sentinel
    }
}

// ---------------- K3: bucket-append scatter (LDS ranks, fat 16B records) --
__global__ __launch_bounds__(256) void append_kernel(
    const float* __restrict__ e,
    const int*   __restrict__ src,
    const int*   __restrict__ dst,
    const float* __restrict__ W_attn,
    const float* __restrict__ W_edge,
    const float* __restrict__ a_src_arr,
    const float* __restrict__ a_dst_arr,
    int*         __restrict__ cursor8,
    float4*      __restrict__ records)
{
    __shared__ int cnt[NBUCK];                   // counts, then rank counters
    __shared__ int base[NBUCK];

    int be  = blockIdx.x;                        // same chunking/class as K1
    int cls = be & 7;
    int tid = threadIdx.x;
    long ebase = (long)be * EB_CHUNK;

    for (int t = tid; t < NBUCK; t += 256) cnt[t] = 0;
    __syncthreads();

    // sweep A: count
    for (int j = 0; j < EB_CHUNK / 256; ++j) {
        long eid = ebase + j * 256 + tid;
        if (eid < N_EDGES) atomicAdd(&cnt[dst[eid] >> 6], 1);
    }
    __syncthreads();

    // allocate per-(block,bucket) contiguous group in this class's sub-region
    for (int t = tid; t < NBUCK; t += 256) {
        int v = cnt[t];
        if (v) base[t] = atomicAdd(&cursor8[t * 8 + cls], v);
        cnt[t] = 0;                              // reuse as rank counter
    }
    __syncthreads();

    // sweep B: compute payload, place at base + LDS rank
    for (int j = 0; j < EB_CHUNK / 256; ++j) {
        long eid = ebase + j * 256 + tid;
        if (eid >= N_EDGES) continue;
        int d = dst[eid];
        int b = d >> 6;
        int r = atomicAdd(&cnt[b], 1);
        int pos = base[b] + r;

        int s = src[eid];
        float2 ev = ((const float2*)e)[eid];
        float ex0 = ev.x * W_edge[0] + ev.y * W_edge[1];
        float ex1 = ev.x * W_edge[2] + ev.y * W_edge[3];
        float a = a_src_arr[s] + a_dst_arr[d]
                + ex0 * W_attn[2 * OUT_DIM] + ex1 * W_attn[2 * OUT_DIM + 1];
        float ea = (a > 0.f) ? a : 0.01f * a;    // leaky_relu(0.01)
        float w  = __expf(ea);

        int w3 = s | ((d & 63) << 17);           // s<2^17; local_d in bits 17..22
        float* rp = (float*)(records + pos);
        __builtin_nontemporal_store(w,                  rp + 0);
        __builtin_nontemporal_store(w * ex0,            rp + 1);
        __builtin_nontemporal_store(w * ex1,            rp + 2);
        __builtin_nontemporal_store(__int_as_float(w3), rp + 3);
    }
}

// ---------------- K4: per-bucket LDS bucketize (in-place) + offsets -------
__global__ __launch_bounds__(256) void bucketize_kernel(
    const int* __restrict__ bases8,
    float4*    __restrict__ records,
    int*       __restrict__ offsets)
{
    __shared__ int4 rec[CAP];                    // 48 KB
    __shared__ unsigned short inv[CAP];          // 6 KB
    __shared__ int hist[64], pfx[64], cur[64];

    int b   = blockIdx.x;
    int tid = threadIdx.x;
    int lo  = bases8[b * 8];
    int hi  = bases8[b * 8 + 8];                 // sentinel covers b = NBUCK-1
    int n   = hi - lo;

    if (tid < 64) hist[tid] = 0;
    __syncthreads();

    int nl = (n <= CAP) ? n : CAP;               // overflow ~22 sigma: loud-fail, no OOB

    // load + local_d histogram
    for (int k = tid; k < nl; k += 256) {
        int4 r = ((const int4*)records)[lo + k];
        rec[k] = r;
        int ld = (r.w >> 17) & 63;
        atomicAdd(&hist[ld], 1);
    }
    __syncthreads();

    // exclusive scan of hist[64]
    if (tid < 64) pfx[tid] = hist[tid];
    __syncthreads();
    for (int off = 1; off < 64; off <<= 1) {
        int t = 0;
        if (tid < 64 && tid >= off) t = pfx[tid - off];
        __syncthreads();
        if (tid < 64) pfx[tid] += t;
        __syncthreads();
    }
    if (tid < 64) {
        pfx[tid] -= hist[tid];                   // exclusive
        cur[tid] = 0;
        int node = (b << 6) + tid;
        if (node < N_NODES) offsets[node] = lo + pfx[tid];
    }
    __syncthreads();

    // build inverse permutation
    for (int k = tid; k < nl; k += 256) {
        int ld = (rec[k].w >> 17) & 63;
        int r  = atomicAdd(&cur[ld], 1);
        inv[pfx[ld] + r] = (unsigned short)k;
    }
    __syncthreads();

    // coalesced in-place writeback in node order, strip packed bits
    for (int k = tid; k < nl; k += 256) {
        int4 v = rec[inv[k]];
        v.w &= 0x1FFFF;
        ((int4*)records)[lo + k] = v;
    }
}

// ---------------- K5: gather (round-8 proven) -----------------------------
__global__ __launch_bounds__(256) void gather_fat_kernel(
    const float4* __restrict__ records,
    const int*    __restrict__ offsets,
    const float*  __restrict__ z,
    const float*  __restrict__ W_e2n,
    float* __restrict__ out)
{
    int node = blockIdx.x * 16 + (threadIdx.x >> 4);
    int lane = threadIdx.x & 15;
    if (node >= N_NODES) return;

    int beg = offsets[node];
    int end = offsets[node + 1];

    const nat_f4* __restrict__ rec = (const nat_f4*)records;

    float acc0 = 0.f, accw0 = 0.f, accx00 = 0.f, accx10 = 0.f;
    float acc1 = 0.f, accw1 = 0.f, accx01 = 0.f, accx11 = 0.f;

    int k = beg;
    for (; k + 1 < end; k += 2) {
        nat_f4 r0 = __builtin_nontemporal_load(rec + k);
        nat_f4 r1 = __builtin_nontemporal_load(rec + k + 1);
        int s0 = __float_as_int(r0.w);
        int s1 = __float_as_int(r1.w);
        float zv0 = z[s0 * OUT_DIM + lane];
        float zv1 = z[s1 * OUT_DIM + lane];
        acc0   += r0.x * zv0;   acc1   += r1.x * zv1;
        accw0  += r0.x;         accw1  += r1.x;
        accx00 += r0.y;         accx01 += r1.y;
        accx10 += r0.z;         accx11 += r1.z;
    }
    if (k < end) {
        nat_f4 r0 = __builtin_nontemporal_load(rec + k);
        int s0 = __float_as_int(r0.w);
        float zv0 = z[s0 * OUT_DIM + lane];
        acc0 += r0.x * zv0;  accw0 += r0.x;  accx00 += r0.y;  accx10 += r0.z;
    }

    float acc   = acc0 + acc1;
    float accw  = accw0 + accw1;
    float accx0 = accx00 + accx01;
    float accx1 = accx10 + accx11;

    float ez  = accx0 * W_e2n[2 * lane] + accx1 * W_e2n[2 * lane + 1];
    float inv = (accw != 0.f) ? (1.f / accw) : 0.f;
    out[(size_t)node * OUT_DIM + lane] = (acc + ez) * inv;
}

// ================= Fallback atomic path (round-1, known-passing) ==========

__global__ __launch_bounds__(256) void node_proj_fb_kernel(
    const float* __restrict__ h,
    const float* __restrict__ W_fc,
    const float* __restrict__ W_attn,
    float* __restrict__ z,
    float* __restrict__ a_src_arr,
    float* __restrict__ a_dst_arr,
    float* __restrict__ denom,
    float* __restrict__ out)
{
    int i = blockIdx.x * blockDim.x + threadIdx.x;
    if (i >= N_NODES) return;

    float acc[OUT_DIM];
#pragma unroll
    for (int j = 0; j < OUT_DIM; ++j) acc[j] = 0.f;

    const float2* __restrict__ hr = (const float2*)(h + (size_t)i * IN_DIM);
#pragma unroll
    for (int kk = 0; kk < IN_DIM / 2; ++kk) {
        float2 hv = hr[kk];
#pragma unroll
        for (int j = 0; j < OUT_DIM; ++j) {
            acc[j] += hv.x * W_fc[j * IN_DIM + 2 * kk]
                    + hv.y * W_fc[j * IN_DIM + 2 * kk + 1];
        }
    }

    float asrc = 0.f, adst = 0.f;
#pragma unroll
    for (int j = 0; j < OUT_DIM; ++j) {
        asrc += acc[j] * W_attn[j];
        adst += acc[j] * W_attn[OUT_DIM + j];
    }

    float4* __restrict__ zrow = (float4*)(z + (size_t)i * OUT_DIM);
    zrow[0] = make_float4(acc[0],  acc[1],  acc[2],  acc[3]);
    zrow[1] = make_float4(acc[4],  acc[5],  acc[6],  acc[7]);
    zrow[2] = make_float4(acc[8],  acc[9],  acc[10], acc[11]);
    zrow[3] = make_float4(acc[12], acc[13], acc[14], acc[15]);

    a_src_arr[i] = asrc;
    a_dst_arr[i] = adst;
    denom[i] = 0.f;

    float4 z4 = make_float4(0.f, 0.f, 0.f, 0.f);
    float4* __restrict__ orow = (float4*)(out + (size_t)i * OUT_DIM);
    orow[0] = z4; orow[1] = z4; orow[2] = z4; orow[3] = z4;
}

__global__ __launch_bounds__(256) void edge_kernel(
    const float* __restrict__ e,
    const int*   __restrict__ src,
    const int*   __restrict__ dst,
    const float* __restrict__ W_attn,
    const float* __restrict__ W_edge,
    const float* __restrict__ W_e2n,
    const float* __restrict__ z,
    const float* __restrict__ a_src_arr,
    const float* __restrict__ a_dst_arr,
    float* __restrict__ denom,
    float* __restrict__ out)
{
    int eid = blockIdx.x * blockDim.x + threadIdx.x;
    if (eid >= N_EDGES) return;

    int s = src[eid];
    int d = dst[eid];

    float2 ev = ((const float2*)e)[eid];
    float ex0 = ev.x * W_edge[0] + ev.y * W_edge[1];
    float ex1 = ev.x * W_edge[2] + ev.y * W_edge[3];

    float a = a_src_arr[s] + a_dst_arr[d]
            + ex0 * W_attn[2 * OUT_DIM] + ex1 * W_attn[2 * OUT_DIM + 1];
    float ea = (a > 0.f) ? a : 0.01f * a;
    float w  = __expf(ea);

    unsafeAtomicAdd(denom + d, w);

    const float4* __restrict__ zrow = (const float4*)(z + (size_t)s * OUT_DIM);
    float4 z0 = zrow[0], z1 = zrow[1], z2 = zrow[2], z3 = zrow[3];

    float* __restrict__ orow = out + (size_t)d * OUT_DIM;
    float zs[OUT_DIM] = { z0.x, z0.y, z0.z, z0.w,
                          z1.x, z1.y, z1.z, z1.w,
                          z2.x, z2.y, z2.z, z2.w,
                          z3.x, z3.y, z3.z, z3.w };
#pragma unroll
    for (int j = 0; j < OUT_DIM; ++j) {
        float ez = ex0 * W_e2n[2 * j] + ex1 * W_e2n[2 * j + 1];
        unsafeAtomicAdd(orow + j, w * (zs[j] + ez));
    }
}

__global__ __launch_bounds__(256) void normalize_kernel(
    float* __restrict__ out, const float* __restrict__ denom)
{
    int tid = blockIdx.x * blockDim.x + threadIdx.x;
    const int total = N_NODES * OUT_DIM / 4;
    if (tid >= total) return;
    int n = tid >> 2;
    float dn = denom[n];
    float inv = (dn != 0.f) ? (1.f / dn) : 0.f;
    float4 v = ((float4*)out)[tid];
    v.x *= inv; v.y *= inv; v.z *= inv; v.w *= inv;
    ((float4*)out)[tid] = v;
}

extern "C" void kernel_launch(void* const* d_in, const int* in_sizes, int n_in,
                              void* d_out, int out_size, void* d_ws, size_t ws_size,
                              hipStream_t stream)
{
    const float* h      = (const float*)d_in[0];
    const float* e      = (const float*)d_in[1];
    const int*   src    = (const int*)  d_in[2];
    const int*   dst    = (const int*)  d_in[3];
    const float* W_fc   = (const float*)d_in[4];
    const float* W_attn = (const float*)d_in[5];
    const float* W_edge = (const float*)d_in[6];
    const float* W_e2n  = (const float*)d_in[7];
    float* out = (float*)d_out;

    // ---- workspace layout (~59 MB < proven 68.4 MB) ----
    char* ws = (char*)d_ws;
    size_t off = 0;
    float* z          = (float*)(ws + off); off += (size_t)N_NODES * OUT_DIM * 4;  // 6.4 MB
    float* a_src_arr  = (float*)(ws + off); off += (size_t)N_NODES * 4;
    float* a_dst_arr  = (float*)(ws + off); off += (size_t)N_NODES * 4;
    int*   cnt8b      = (int*)  (ws + off); off += (size_t)NSEG * 4;               // 50,016 B
    int*   bases8     = (int*)  (ws + off); off += (size_t)(NSEG + 4) * 4;         // 50,032 B (sentinel+pad)
    int*   cursor8    = (int*)  (ws + off); off += (size_t)NSEG * 4;
    float* denom      = (float*)(ws + off);                                         // fallback alias
    int*   offsets    = (int*)  (ws + off); off += (size_t)(N_NODES + 4) * 4;      // 400,016 B
    float4* records   = (float4*)(ws + off); off += (size_t)N_EDGES * 16;           // 51.2 MB
    const size_t need = off;

    if (ws_size >= need) {
        zero_seg_kernel<<<(NSEG + 255) / 256, 256, 0, stream>>>(cnt8b);

        fused_proj_count_kernel<<<NBLK + NEB, 256, 0, stream>>>(
            h, W_fc, W_attn, dst, z, a_src_arr, a_dst_arr, cnt8b);

        scan_seg_kernel<<<1, 256, 0, stream>>>(cnt8b, bases8, cursor8, offsets);

        append_kernel<<<NEB, 256, 0, stream>>>(
            e, src, dst, W_attn, W_edge, a_src_arr, a_dst_arr, cursor8, records);

        bucketize_kernel<<<NBUCK, 256, 0, stream>>>(bases8, records, offsets);

        gather_fat_kernel<<<(N_NODES + 15) / 16, 256, 0, stream>>>(
            records, offsets, z, W_e2n, out);
    } else {
        // -------- round-1 atomic fallback (needs ~8 MB) --------
        node_proj_fb_kernel<<<NBLK, 256, 0, stream>>>(
            h, W_fc, W_attn, z, a_src_arr, a_dst_arr, denom, out);

        edge_kernel<<<(N_EDGES + 255) / 256, 256, 0, stream>>>(
            e, src, dst, W_attn, W_edge, W_e2n, z, a_src_arr, a_dst_arr, denom, out);

        normalize_kernel<<<(N_NODES * OUT_DIM / 4 + 255) / 256, 256, 0, stream>>>(
            out, denom);
    }
}

// Round 10
// 379.572 us; speedup vs baseline: 7.6118x; 1.2157x over previous
//
#include <hip/hip_runtime.h>

#define N_NODES 100000
#define N_EDGES 3200000
#define IN_DIM  62
#define OUT_DIM 16
#define EB_CHUNK 16384                           // edges per count/append block
#define NEB    ((N_EDGES + EB_CHUNK - 1) / EB_CHUNK)   // 196 edge blocks
#define NPB    ((N_NODES + 1023) / 1024)         // 98 node-proj blocks (1024 thr)
#define NBUCK  ((N_NODES + 63) / 64)             // 1563 buckets (dst>>6)
#define NSEG   (NBUCK * 8)                       // 12504 (bucket,class) segments
#define CAP    3072                              // records/bucket LDS cap (avg 2048, +22 sigma)

// ---------------- K0: zero the (bucket,class) counters ----------------
__global__ __launch_bounds__(256) void zero_seg_kernel(int* __restrict__ cnt8b)
{
    int i = blockIdx.x * blockDim.x + threadIdx.x;
    if (i < NSEG) cnt8b[i] = 0;
}

// ---------------- K1: fused node projection + LDS-aggregated bucket count
// blocks [0,NPB): node proj; blocks [NPB, NPB+NEB): edge count
__global__ __launch_bounds__(1024) void fused_proj_count_kernel(
    const float* __restrict__ h,
    const float* __restrict__ W_fc,
    const float* __restrict__ W_attn,
    const int*   __restrict__ dst,
    float* __restrict__ z,
    float* __restrict__ a_src_arr,
    float* __restrict__ a_dst_arr,
    int*   __restrict__ cnt8b)
{
    __shared__ int cnt[NBUCK];                   // 6.25 KB

    if (blockIdx.x < NPB) {
        int i = blockIdx.x * 1024 + threadIdx.x;
        if (i >= N_NODES) return;

        float acc[OUT_DIM];
#pragma unroll
        for (int j = 0; j < OUT_DIM; ++j) acc[j] = 0.f;

        const float2* __restrict__ hr = (const float2*)(h + (size_t)i * IN_DIM);
#pragma unroll
        for (int kk = 0; kk < IN_DIM / 2; ++kk) {
            float2 hv = hr[kk];
#pragma unroll
            for (int j = 0; j < OUT_DIM; ++j) {
                acc[j] += hv.x * W_fc[j * IN_DIM + 2 * kk]
                        + hv.y * W_fc[j * IN_DIM + 2 * kk + 1];
            }
        }

        float asrc = 0.f, adst = 0.f;
#pragma unroll
        for (int j = 0; j < OUT_DIM; ++j) {
            asrc += acc[j] * W_attn[j];
            adst += acc[j] * W_attn[OUT_DIM + j];
        }

        float4* __restrict__ zrow = (float4*)(z + (size_t)i * OUT_DIM);
        zrow[0] = make_float4(acc[0],  acc[1],  acc[2],  acc[3]);
        zrow[1] = make_float4(acc[4],  acc[5],  acc[6],  acc[7]);
        zrow[2] = make_float4(acc[8],  acc[9],  acc[10], acc[11]);
        zrow[3] = make_float4(acc[12], acc[13], acc[14], acc[15]);

        a_src_arr[i] = asrc;
        a_dst_arr[i] = adst;
    } else {
        int be  = blockIdx.x - NPB;              // edge-chunk index (must match K3)
        int cls = be & 7;
        int tid = threadIdx.x;
        long ebase = (long)be * EB_CHUNK;

        for (int t = tid; t < NBUCK; t += 1024) cnt[t] = 0;
        __syncthreads();

        for (int j = 0; j < EB_CHUNK / 1024; ++j) {
            long eid = ebase + j * 1024 + tid;
            if (eid < N_EDGES) atomicAdd(&cnt[dst[eid] >> 6], 1);
        }
        __syncthreads();

        for (int t = tid; t < NBUCK; t += 1024) {
            int v = cnt[t];
            if (v) atomicAdd(&cnt8b[t * 8 + cls], v);
        }
    }
}

// ---------------- K2: exclusive scan of 12504 segment counts (1 block) ----
__global__ __launch_bounds__(256) void scan_seg_kernel(
    const int* __restrict__ cnt8b,
    int* __restrict__ bases8,
    int* __restrict__ cursor8)
{
    __shared__ int sums[256];
    int tid = threadIdx.x;
    const int PER = (NSEG + 255) / 256;          // 49

    int s = 0;
    for (int k = 0; k < PER; ++k) {
        int i = tid * PER + k;
        if (i < NSEG) s += cnt8b[i];
    }
    sums[tid] = s;
    __syncthreads();
    for (int off = 1; off < 256; off <<= 1) {
        int t = (tid >= off) ? sums[tid - off] : 0;
        __syncthreads();
        sums[tid] += t;
        __syncthreads();
    }
    int run = sums[tid] - s;                     // exclusive base for this chunk
    for (int k = 0; k < PER; ++k) {
        int i = tid * PER + k;
        if (i < NSEG) {
            int v = cnt8b[i];
            bases8[i]  = run;
            cursor8[i] = run;
            run += v;
        }
    }
    if (tid == 0) bases8[NSEG] = N_EDGES;        // sentinel
}

// ---------------- K3: bucket-append scatter (LDS ranks, fat 16B records) --
__global__ __launch_bounds__(1024) void append_kernel(
    const float* __restrict__ e,
    const int*   __restrict__ src,
    const int*   __restrict__ dst,
    const float* __restrict__ W_attn,
    const float* __restrict__ W_edge,
    const float* __restrict__ a_src_arr,
    const float* __restrict__ a_dst_arr,
    int*         __restrict__ cursor8,
    float4*      __restrict__ records)
{
    __shared__ int cnt[NBUCK];                   // counts, then rank counters
    __shared__ int base[NBUCK];

    int be  = blockIdx.x;                        // same chunking/class as K1
    int cls = be & 7;
    int tid = threadIdx.x;
    long ebase = (long)be * EB_CHUNK;

    for (int t = tid; t < NBUCK; t += 1024) cnt[t] = 0;
    __syncthreads();

    // sweep A: count
    for (int j = 0; j < EB_CHUNK / 1024; ++j) {
        long eid = ebase + j * 1024 + tid;
        if (eid < N_EDGES) atomicAdd(&cnt[dst[eid] >> 6], 1);
    }
    __syncthreads();

    // allocate per-(block,bucket) contiguous group in this class's sub-region
    for (int t = tid; t < NBUCK; t += 1024) {
        int v = cnt[t];
        if (v) base[t] = atomicAdd(&cursor8[t * 8 + cls], v);
        cnt[t] = 0;                              // reuse as rank counter
    }
    __syncthreads();

    // sweep B: compute payload, place at base + LDS rank
    for (int j = 0; j < EB_CHUNK / 1024; ++j) {
        long eid = ebase + j * 1024 + tid;
        if (eid >= N_EDGES) continue;
        int d = dst[eid];
        int b = d >> 6;
        int r = atomicAdd(&cnt[b], 1);
        int pos = base[b] + r;

        int s = src[eid];
        float2 ev = ((const float2*)e)[eid];
        float ex0 = ev.x * W_edge[0] + ev.y * W_edge[1];
        float ex1 = ev.x * W_edge[2] + ev.y * W_edge[3];
        float a = a_src_arr[s] + a_dst_arr[d]
                + ex0 * W_attn[2 * OUT_DIM] + ex1 * W_attn[2 * OUT_DIM + 1];
        float ea = (a > 0.f) ? a : 0.01f * a;    // leaky_relu(0.01)
        float w  = __expf(ea);

        int w3 = s | ((d & 63) << 17);           // s<2^17; local_d in bits 17..22
        float* rp = (float*)(records + pos);
        __builtin_nontemporal_store(w,                  rp + 0);
        __builtin_nontemporal_store(w * ex0,            rp + 1);
        __builtin_nontemporal_store(w * ex1,            rp + 2);
        __builtin_nontemporal_store(__int_as_float(w3), rp + 3);
    }
}

// ---------------- K4: fused per-bucket LDS bucketize + gather -------------
// one 1024-thread block per bucket; 64 groups of 16 lanes, one group per node
__global__ __launch_bounds__(1024) void bucket_gather_kernel(
    const int*    __restrict__ bases8,
    const float4* __restrict__ records,
    const float*  __restrict__ z,
    const float*  __restrict__ W_e2n,
    float* __restrict__ out)
{
    __shared__ int4 rec[CAP];                    // 48 KB
    __shared__ unsigned short inv[CAP];          // 6 KB
    __shared__ int hist[64], pfx[64], cur[64];

    int b   = blockIdx.x;
    int tid = threadIdx.x;
    int lo  = bases8[b * 8];
    int hi  = bases8[b * 8 + 8];                 // sentinel covers b = NBUCK-1
    int n   = hi - lo;

    if (tid < 64) { hist[tid] = 0; cur[tid] = 0; }
    __syncthreads();

    int nl = (n <= CAP) ? n : CAP;               // overflow ~22 sigma: loud-fail, no OOB

    // load + local_d histogram
    for (int k = tid; k < nl; k += 1024) {
        int4 r = ((const int4*)records)[lo + k];
        rec[k] = r;
        atomicAdd(&hist[(r.w >> 17) & 63], 1);
    }
    __syncthreads();

    // exclusive scan of hist[64]
    if (tid < 64) pfx[tid] = hist[tid];
    __syncthreads();
    for (int off = 1; off < 64; off <<= 1) {
        int t = 0;
        if (tid < 64 && tid >= off) t = pfx[tid - off];
        __syncthreads();
        if (tid < 64) pfx[tid] += t;
        __syncthreads();
    }
    if (tid < 64) pfx[tid] -= hist[tid];         // exclusive
    __syncthreads();

    // build inverse permutation
    for (int k = tid; k < nl; k += 1024) {
        int ld = (rec[k].w >> 17) & 63;
        int r  = atomicAdd(&cur[ld], 1);
        inv[pfx[ld] + r] = (unsigned short)k;
    }
    __syncthreads();

    // gather straight from LDS: group = node, 16 lanes = features
    int ld   = tid >> 4;
    int lane = tid & 15;
    int node = (b << 6) + ld;
    if (node >= N_NODES) return;

    int m    = hist[ld];
    int base = pfx[ld];

    float acc0 = 0.f, accw0 = 0.f, accx00 = 0.f, accx10 = 0.f;
    float acc1 = 0.f, accw1 = 0.f, accx01 = 0.f, accx11 = 0.f;

    int i = 0;
    for (; i + 1 < m; i += 2) {
        int4 r0 = rec[inv[base + i]];
        int4 r1 = rec[inv[base + i + 1]];
        int s0 = r0.w & 0x1FFFF;
        int s1 = r1.w & 0x1FFFF;
        float zv0 = z[s0 * OUT_DIM + lane];
        float zv1 = z[s1 * OUT_DIM + lane];
        float w0 = __int_as_float(r0.x), w1 = __int_as_float(r1.x);
        acc0   += w0 * zv0;                acc1   += w1 * zv1;
        accw0  += w0;                      accw1  += w1;
        accx00 += __int_as_float(r0.y);    accx01 += __int_as_float(r1.y);
        accx10 += __int_as_float(r0.z);    accx11 += __int_as_float(r1.z);
    }
    if (i < m) {
        int4 r0 = rec[inv[base + i]];
        int s0 = r0.w & 0x1FFFF;
        float zv0 = z[s0 * OUT_DIM + lane];
        float w0 = __int_as_float(r0.x);
        acc0 += w0 * zv0;  accw0 += w0;
        accx00 += __int_as_float(r0.y);  accx10 += __int_as_float(r0.z);
    }

    float acc   = acc0 + acc1;
    float accw  = accw0 + accw1;
    float accx0 = accx00 + accx01;
    float accx1 = accx10 + accx11;

    float ez   = accx0 * W_e2n[2 * lane] + accx1 * W_e2n[2 * lane + 1];
    float invw = (accw != 0.f) ? (1.f / accw) : 0.f;
    out[(size_t)node * OUT_DIM + lane] = (acc + ez) * invw;
}

// ================= Fallback atomic path (round-1, known-passing) ==========

__global__ __launch_bounds__(256) void node_proj_fb_kernel(
    const float* __restrict__ h,
    const float* __restrict__ W_fc,
    const float* __restrict__ W_attn,
    float* __restrict__ z,
    float* __restrict__ a_src_arr,
    float* __restrict__ a_dst_arr,
    float* __restrict__ denom,
    float* __restrict__ out)
{
    int i = blockIdx.x * blockDim.x + threadIdx.x;
    if (i >= N_NODES) return;

    float acc[OUT_DIM];
#pragma unroll
    for (int j = 0; j < OUT_DIM; ++j) acc[j] = 0.f;

    const float2* __restrict__ hr = (const float2*)(h + (size_t)i * IN_DIM);
#pragma unroll
    for (int kk = 0; kk < IN_DIM / 2; ++kk) {
        float2 hv = hr[kk];
#pragma unroll
        for (int j = 0; j < OUT_DIM; ++j) {
            acc[j] += hv.x * W_fc[j * IN_DIM + 2 * kk]
                    + hv.y * W_fc[j * IN_DIM + 2 * kk + 1];
        }
    }

    float asrc = 0.f, adst = 0.f;
#pragma unroll
    for (int j = 0; j < OUT_DIM; ++j) {
        asrc += acc[j] * W_attn[j];
        adst += acc[j] * W_attn[OUT_DIM + j];
    }

    float4* __restrict__ zrow = (float4*)(z + (size_t)i * OUT_DIM);
    zrow[0] = make_float4(acc[0],  acc[1],  acc[2],  acc[3]);
    zrow[1] = make_float4(acc[4],  acc[5],  acc[6],  acc[7]);
    zrow[2] = make_float4(acc[8],  acc[9],  acc[10], acc[11]);
    zrow[3] = make_float4(acc[12], acc[13], acc[14], acc[15]);

    a_src_arr[i] = asrc;
    a_dst_arr[i] = adst;
    denom[i] = 0.f;

    float4 z4 = make_float4(0.f, 0.f, 0.f, 0.f);
    float4* __restrict__ orow = (float4*)(out + (size_t)i * OUT_DIM);
    orow[0] = z4; orow[1] = z4; orow[2] = z4; orow[3] = z4;
}

__global__ __launch_bounds__(256) void edge_kernel(
    const float* __restrict__ e,
    const int*   __restrict__ src,
    const int*   __restrict__ dst,
    const float* __restrict__ W_attn,
    const float* __restrict__ W_edge,
    const float* __restrict__ W_e2n,
    const float* __restrict__ z,
    const float* __restrict__ a_src_arr,
    const float* __restrict__ a_dst_arr,
    float* __restrict__ denom,
    float* __restrict__ out)
{
    int eid = blockIdx.x * blockDim.x + threadIdx.x;
    if (eid >= N_EDGES) return;

    int s = src[eid];
    int d = dst[eid];

    float2 ev = ((const float2*)e)[eid];
    float ex0 = ev.x * W_edge[0] + ev.y * W_edge[1];
    float ex1 = ev.x * W_edge[2] + ev.y * W_edge[3];

    float a = a_src_arr[s] + a_dst_arr[d]
            + ex0 * W_attn[2 * OUT_DIM] + ex1 * W_attn[2 * OUT_DIM + 1];
    float ea = (a > 0.f) ? a : 0.01f * a;
    float w  = __expf(ea);

    unsafeAtomicAdd(denom + d, w);

    const float4* __restrict__ zrow = (const float4*)(z + (size_t)s * OUT_DIM);
    float4 z0 = zrow[0], z1 = zrow[1], z2 = zrow[2], z3 = zrow[3];

    float* __restrict__ orow = out + (size_t)d * OUT_DIM;
    float zs[OUT_DIM] = { z0.x, z0.y, z0.z, z0.w,
                          z1.x, z1.y, z1.z, z1.w,
                          z2.x, z2.y, z2.z, z2.w,
                          z3.x, z3.y, z3.z, z3.w };
#pragma unroll
    for (int j = 0; j < OUT_DIM; ++j) {
        float ez = ex0 * W_e2n[2 * j] + ex1 * W_e2n[2 * j + 1];
        unsafeAtomicAdd(orow + j, w * (zs[j] + ez));
    }
}

__global__ __launch_bounds__(256) void normalize_kernel(
    float* __restrict__ out, const float* __restrict__ denom)
{
    int tid = blockIdx.x * blockDim.x + threadIdx.x;
    const int total = N_NODES * OUT_DIM / 4;
    if (tid >= total) return;
    int n = tid >> 2;
    float dn = denom[n];
    float inv = (dn != 0.f) ? (1.f / dn) : 0.f;
    float4 v = ((float4*)out)[tid];
    v.x *= inv; v.y *= inv; v.z *= inv; v.w *= inv;
    ((float4*)out)[tid] = v;
}

extern "C" void kernel_launch(void* const* d_in, const int* in_sizes, int n_in,
                              void* d_out, int out_size, void* d_ws, size_t ws_size,
                              hipStream_t stream)
{
    const float* h      = (const float*)d_in[0];
    const float* e      = (const float*)d_in[1];
    const int*   src    = (const int*)  d_in[2];
    const int*   dst    = (const int*)  d_in[3];
    const float* W_fc   = (const float*)d_in[4];
    const float* W_attn = (const float*)d_in[5];
    const float* W_edge = (const float*)d_in[6];
    const float* W_e2n  = (const float*)d_in[7];
    float* out = (float*)d_out;

    // ---- workspace layout (~59 MB < proven 68.4 MB) ----
    char* ws = (char*)d_ws;
    size_t off = 0;
    float* z          = (float*)(ws + off); off += (size_t)N_NODES * OUT_DIM * 4;  // 6.4 MB
    float* a_src_arr  = (float*)(ws + off); off += (size_t)N_NODES * 4;
    float* a_dst_arr  = (float*)(ws + off); off += (size_t)N_NODES * 4;
    float* denom      = (float*)(ws + off); off += (size_t)N_NODES * 4;            // fallback only
    int*   cnt8b      = (int*)  (ws + off); off += (size_t)NSEG * 4;
    int*   bases8     = (int*)  (ws + off); off += (size_t)(NSEG + 4) * 4;         // +sentinel
    int*   cursor8    = (int*)  (ws + off); off += (size_t)NSEG * 4;
    float4* records   = (float4*)(ws + off); off += (size_t)N_EDGES * 16;           // 51.2 MB
    const size_t need = off;

    if (ws_size >= need) {
        zero_seg_kernel<<<(NSEG + 255) / 256, 256, 0, stream>>>(cnt8b);

        fused_proj_count_kernel<<<NPB + NEB, 1024, 0, stream>>>(
            h, W_fc, W_attn, dst, z, a_src_arr, a_dst_arr, cnt8b);

        scan_seg_kernel<<<1, 256, 0, stream>>>(cnt8b, bases8, cursor8);

        append_kernel<<<NEB, 1024, 0, stream>>>(
            e, src, dst, W_attn, W_edge, a_src_arr, a_dst_arr, cursor8, records);

        bucket_gather_kernel<<<NBUCK, 1024, 0, stream>>>(
            bases8, records, z, W_e2n, out);
    } else {
        // -------- round-1 atomic fallback (needs ~8 MB) --------
        node_proj_fb_kernel<<<(N_NODES + 255) / 256, 256, 0, stream>>>(
            h, W_fc, W_attn, z, a_src_arr, a_dst_arr, denom, out);

        edge_kernel<<<(N_EDGES + 255) / 256, 256, 0, stream>>>(
            e, src, dst, W_attn, W_edge, W_e2n, z, a_src_arr, a_dst_arr, denom, out);

        normalize_kernel<<<(N_NODES * OUT_DIM / 4 + 255) / 256, 256, 0, stream>>>(
            out, denom);
    }
}

// Round 11
// 335.764 us; speedup vs baseline: 8.6049x; 1.1305x over previous
//
#include <hip/hip_runtime.h>
#include <hip/hip_fp16.h>

#define N_NODES 100000
#define N_EDGES 3200000
#define IN_DIM  62
#define OUT_DIM 16
#define EB_CHUNK 16384                           // edges per count/append block
#define NEB    ((N_EDGES + EB_CHUNK - 1) / EB_CHUNK)   // 196 edge blocks
#define NPB    ((N_NODES + 1023) / 1024)         // 98 node-proj blocks (1024 thr)
#define NBUCK  ((N_NODES + 63) / 64)             // 1563 buckets (dst>>6)
#define NSEG   (NBUCK * 8)                       // 12504 (bucket,class) segments
#define CAP    3072                              // records/bucket LDS cap (avg 2048, +22 sigma)

// ---------------- K0: zero the (bucket,class) counters ----------------
__global__ __launch_bounds__(256) void zero_seg_kernel(int* __restrict__ cnt8b)
{
    int i = blockIdx.x * blockDim.x + threadIdx.x;
    if (i < NSEG) cnt8b[i] = 0;
}

// ---------------- K1: fused node projection (fp16 z) + bucket count ------
__global__ __launch_bounds__(1024) void fused_proj_count_kernel(
    const float* __restrict__ h,
    const float* __restrict__ W_fc,
    const float* __restrict__ W_attn,
    const int*   __restrict__ dst,
    __half* __restrict__ zh,
    float* __restrict__ a_src_arr,
    float* __restrict__ a_dst_arr,
    int*   __restrict__ cnt8b)
{
    __shared__ int cnt[NBUCK];                   // 6.25 KB

    if (blockIdx.x < NPB) {
        int i = blockIdx.x * 1024 + threadIdx.x;
        if (i >= N_NODES) return;

        float acc[OUT_DIM];
#pragma unroll
        for (int j = 0; j < OUT_DIM; ++j) acc[j] = 0.f;

        const float2* __restrict__ hr = (const float2*)(h + (size_t)i * IN_DIM);
#pragma unroll
        for (int kk = 0; kk < IN_DIM / 2; ++kk) {
            float2 hv = hr[kk];
#pragma unroll
            for (int j = 0; j < OUT_DIM; ++j) {
                acc[j] += hv.x * W_fc[j * IN_DIM + 2 * kk]
                        + hv.y * W_fc[j * IN_DIM + 2 * kk + 1];
            }
        }

        float asrc = 0.f, adst = 0.f;
#pragma unroll
        for (int j = 0; j < OUT_DIM; ++j) {
            asrc += acc[j] * W_attn[j];
            adst += acc[j] * W_attn[OUT_DIM + j];
        }

        union { __half hx[16]; uint4 q[2]; } u;
#pragma unroll
        for (int j = 0; j < OUT_DIM; ++j) u.hx[j] = __float2half(acc[j]);
        uint4* __restrict__ zrow = (uint4*)(zh + (size_t)i * OUT_DIM);
        zrow[0] = u.q[0];
        zrow[1] = u.q[1];

        a_src_arr[i] = asrc;
        a_dst_arr[i] = adst;
    } else {
        int be  = blockIdx.x - NPB;              // edge-chunk index (must match K3)
        int cls = be & 7;
        int tid = threadIdx.x;
        long ebase = (long)be * EB_CHUNK;

        for (int t = tid; t < NBUCK; t += 1024) cnt[t] = 0;
        __syncthreads();

        for (int j = 0; j < EB_CHUNK / 1024; ++j) {
            long eid = ebase + j * 1024 + tid;
            if (eid < N_EDGES) atomicAdd(&cnt[dst[eid] >> 6], 1);
        }
        __syncthreads();

        for (int t = tid; t < NBUCK; t += 1024) {
            int v = cnt[t];
            if (v) atomicAdd(&cnt8b[t * 8 + cls], v);
        }
    }
}

// ---------------- K2: exclusive scan of 12504 segment counts (1 block) ----
__global__ __launch_bounds__(256) void scan_seg_kernel(
    const int* __restrict__ cnt8b,
    int* __restrict__ bases8,
    int* __restrict__ cursor8)
{
    __shared__ int sums[256];
    int tid = threadIdx.x;
    const int PER = (NSEG + 255) / 256;          // 49

    int s = 0;
    for (int k = 0; k < PER; ++k) {
        int i = tid * PER + k;
        if (i < NSEG) s += cnt8b[i];
    }
    sums[tid] = s;
    __syncthreads();
    for (int off = 1; off < 256; off <<= 1) {
        int t = (tid >= off) ? sums[tid - off] : 0;
        __syncthreads();
        sums[tid] += t;
        __syncthreads();
    }
    int run = sums[tid] - s;                     // exclusive base for this chunk
    for (int k = 0; k < PER; ++k) {
        int i = tid * PER + k;
        if (i < NSEG) {
            int v = cnt8b[i];
            bases8[i]  = run;
            cursor8[i] = run;
            run += v;
        }
    }
    if (tid == 0) bases8[NSEG] = N_EDGES;        // sentinel
}

// ---------------- K3: append with in-LDS SORTED emission -------------------
// B1 builds a bucket-sorted permutation in LDS; B2 emits records in sorted
// order so consecutive lanes write consecutive addresses (merged lines).
__global__ __launch_bounds__(1024) void append_kernel(
    const float* __restrict__ e,
    const int*   __restrict__ src,
    const int*   __restrict__ dst,
    const float* __restrict__ W_attn,
    const float* __restrict__ W_edge,
    const float* __restrict__ a_src_arr,
    const float* __restrict__ a_dst_arr,
    int*         __restrict__ cursor8,
    float4*      __restrict__ records)
{
    __shared__ int cnt[NBUCK];                   // counts -> rank counters
    __shared__ int pfx[NBUCK];                   // block-local exclusive prefix
    __shared__ int combo[NBUCK];                 // global_base - pfx
    __shared__ int inv[EB_CHUNK];                // sorted perm: p | (b<<14); 64 KB

    int be  = blockIdx.x;                        // same chunking/class as K1
    int cls = be & 7;
    int tid = threadIdx.x;
    long ebase = (long)be * EB_CHUNK;
    int chunk_n = (int)min((long)EB_CHUNK, (long)N_EDGES - ebase);

    for (int t = tid; t < NBUCK; t += 1024) cnt[t] = 0;
    __syncthreads();

    // sweep A: count
    for (int p = tid; p < chunk_n; p += 1024)
        atomicAdd(&cnt[dst[ebase + p] >> 6], 1);
    __syncthreads();

    // block-wide exclusive scan of cnt[NBUCK] (2 elems/thread; inv as scratch)
    int b0 = 2 * tid, b1 = 2 * tid + 1;
    int c0 = (b0 < NBUCK) ? cnt[b0] : 0;
    int c1 = (b1 < NBUCK) ? cnt[b1] : 0;
    int ts = c0 + c1;
    inv[tid] = ts;
    __syncthreads();
    for (int off = 1; off < 1024; off <<= 1) {
        int t = (tid >= off) ? inv[tid - off] : 0;
        __syncthreads();
        inv[tid] += t;
        __syncthreads();
    }
    int texcl = inv[tid] - ts;
    if (b0 < NBUCK) pfx[b0] = texcl;
    if (b1 < NBUCK) pfx[b1] = texcl + c0;
    __syncthreads();

    // allocate global group per touched bucket; zero rank counters
    for (int t = tid; t < NBUCK; t += 1024) {
        int v = cnt[t];
        if (v) {
            int gbase = atomicAdd(&cursor8[t * 8 + cls], v);
            combo[t] = gbase - pfx[t];
        }
        cnt[t] = 0;
    }
    __syncthreads();

    // sweep B1: build sorted permutation
    for (int p = tid; p < chunk_n; p += 1024) {
        int b = dst[ebase + p] >> 6;
        int r = atomicAdd(&cnt[b], 1);
        inv[pfx[b] + r] = p | (b << 14);
    }
    __syncthreads();

    // sweep B2: emit in sorted order (merged-line nt stores)
    for (int p = tid; p < chunk_n; p += 1024) {
        int m = inv[p];
        int k = m & 0x3FFF;
        int b = m >> 14;
        long eid = ebase + k;

        int d = dst[eid];                        // L2-hot window re-reads
        int s = src[eid];
        float2 ev = ((const float2*)e)[eid];
        float ex0 = ev.x * W_edge[0] + ev.y * W_edge[1];
        float ex1 = ev.x * W_edge[2] + ev.y * W_edge[3];
        float a = a_src_arr[s] + a_dst_arr[d]
                + ex0 * W_attn[2 * OUT_DIM] + ex1 * W_attn[2 * OUT_DIM + 1];
        float ea = (a > 0.f) ? a : 0.01f * a;    // leaky_relu(0.01)
        float w  = __expf(ea);

        int w3 = s | ((d & 63) << 17);           // s<2^17; local_d in bits 17..22
        int pos = combo[b] + p;                  // == global_base + rank
        float* rp = (float*)(records + pos);
        __builtin_nontemporal_store(w,                  rp + 0);
        __builtin_nontemporal_store(w * ex0,            rp + 1);
        __builtin_nontemporal_store(w * ex1,            rp + 2);
        __builtin_nontemporal_store(__int_as_float(w3), rp + 3);
    }
}

// ---------------- K4: fused per-bucket LDS bucketize + gather (fp16 z) ----
__global__ __launch_bounds__(1024) void bucket_gather_kernel(
    const int*    __restrict__ bases8,
    const float4* __restrict__ records,
    const __half* __restrict__ zh,
    const float*  __restrict__ W_e2n,
    float* __restrict__ out)
{
    __shared__ int4 rec[CAP];                    // 48 KB
    __shared__ unsigned short inv[CAP];          // 6 KB
    __shared__ int hist[64], pfx[64], cur[64];

    int b   = blockIdx.x;
    int tid = threadIdx.x;
    int lo  = bases8[b * 8];
    int hi  = bases8[b * 8 + 8];                 // sentinel covers b = NBUCK-1
    int n   = hi - lo;

    if (tid < 64) { hist[tid] = 0; cur[tid] = 0; }
    __syncthreads();

    int nl = (n <= CAP) ? n : CAP;               // overflow ~22 sigma: loud-fail, no OOB

    for (int k = tid; k < nl; k += 1024) {
        int4 r = ((const int4*)records)[lo + k];
        rec[k] = r;
        atomicAdd(&hist[(r.w >> 17) & 63], 1);
    }
    __syncthreads();

    if (tid < 64) pfx[tid] = hist[tid];
    __syncthreads();
    for (int off = 1; off < 64; off <<= 1) {
        int t = 0;
        if (tid < 64 && tid >= off) t = pfx[tid - off];
        __syncthreads();
        if (tid < 64) pfx[tid] += t;
        __syncthreads();
    }
    if (tid < 64) pfx[tid] -= hist[tid];         // exclusive
    __syncthreads();

    for (int k = tid; k < nl; k += 1024) {
        int ld = (rec[k].w >> 17) & 63;
        int r  = atomicAdd(&cur[ld], 1);
        inv[pfx[ld] + r] = (unsigned short)k;
    }
    __syncthreads();

    // gather straight from LDS: group = node, 16 lanes = features
    int ld   = tid >> 4;
    int lane = tid & 15;
    int node = (b << 6) + ld;
    if (node >= N_NODES) return;

    int m    = hist[ld];
    int base = pfx[ld];

    float acc0 = 0.f, accw0 = 0.f, accx00 = 0.f, accx10 = 0.f;
    float acc1 = 0.f, accw1 = 0.f, accx01 = 0.f, accx11 = 0.f;

    int i = 0;
    for (; i + 1 < m; i += 2) {
        int4 r0 = rec[inv[base + i]];
        int4 r1 = rec[inv[base + i + 1]];
        int s0 = r0.w & 0x1FFFF;
        int s1 = r1.w & 0x1FFFF;
        float zv0 = __half2float(zh[s0 * OUT_DIM + lane]);
        float zv1 = __half2float(zh[s1 * OUT_DIM + lane]);
        float w0 = __int_as_float(r0.x), w1 = __int_as_float(r1.x);
        acc0   += w0 * zv0;                acc1   += w1 * zv1;
        accw0  += w0;                      accw1  += w1;
        accx00 += __int_as_float(r0.y);    accx01 += __int_as_float(r1.y);
        accx10 += __int_as_float(r0.z);    accx11 += __int_as_float(r1.z);
    }
    if (i < m) {
        int4 r0 = rec[inv[base + i]];
        int s0 = r0.w & 0x1FFFF;
        float zv0 = __half2float(zh[s0 * OUT_DIM + lane]);
        float w0 = __int_as_float(r0.x);
        acc0 += w0 * zv0;  accw0 += w0;
        accx00 += __int_as_float(r0.y);  accx10 += __int_as_float(r0.z);
    }

    float acc   = acc0 + acc1;
    float accw  = accw0 + accw1;
    float accx0 = accx00 + accx01;
    float accx1 = accx10 + accx11;

    float ez   = accx0 * W_e2n[2 * lane] + accx1 * W_e2n[2 * lane + 1];
    float invw = (accw != 0.f) ? (1.f / accw) : 0.f;
    out[(size_t)node * OUT_DIM + lane] = (acc + ez) * invw;
}

// ================= Fallback atomic path (round-1, known-passing) ==========

__global__ __launch_bounds__(256) void node_proj_fb_kernel(
    const float* __restrict__ h,
    const float* __restrict__ W_fc,
    const float* __restrict__ W_attn,
    float* __restrict__ z,
    float* __restrict__ a_src_arr,
    float* __restrict__ a_dst_arr,
    float* __restrict__ denom,
    float* __restrict__ out)
{
    int i = blockIdx.x * blockDim.x + threadIdx.x;
    if (i >= N_NODES) return;

    float acc[OUT_DIM];
#pragma unroll
    for (int j = 0; j < OUT_DIM; ++j) acc[j] = 0.f;

    const float2* __restrict__ hr = (const float2*)(h + (size_t)i * IN_DIM);
#pragma unroll
    for (int kk = 0; kk < IN_DIM / 2; ++kk) {
        float2 hv = hr[kk];
#pragma unroll
        for (int j = 0; j < OUT_DIM; ++j) {
            acc[j] += hv.x * W_fc[j * IN_DIM + 2 * kk]
                    + hv.y * W_fc[j * IN_DIM + 2 * kk + 1];
        }
    }

    float asrc = 0.f, adst = 0.f;
#pragma unroll
    for (int j = 0; j < OUT_DIM; ++j) {
        asrc += acc[j] * W_attn[j];
        adst += acc[j] * W_attn[OUT_DIM + j];
    }

    float4* __restrict__ zrow = (float4*)(z + (size_t)i * OUT_DIM);
    zrow[0] = make_float4(acc[0],  acc[1],  acc[2],  acc[3]);
    zrow[1] = make_float4(acc[4],  acc[5],  acc[6],  acc[7]);
    zrow[2] = make_float4(acc[8],  acc[9],  acc[10], acc[11]);
    zrow[3] = make_float4(acc[12], acc[13], acc[14], acc[15]);

    a_src_arr[i] = asrc;
    a_dst_arr[i] = adst;
    denom[i] = 0.f;

    float4 z4 = make_float4(0.f, 0.f, 0.f, 0.f);
    float4* __restrict__ orow = (float4*)(out + (size_t)i * OUT_DIM);
    orow[0] = z4; orow[1] = z4; orow[2] = z4; orow[3] = z4;
}

__global__ __launch_bounds__(256) void edge_kernel(
    const float* __restrict__ e,
    const int*   __restrict__ src,
    const int*   __restrict__ dst,
    const float* __restrict__ W_attn,
    const float* __restrict__ W_edge,
    const float* __restrict__ W_e2n,
    const float* __restrict__ z,
    const float* __restrict__ a_src_arr,
    const float* __restrict__ a_dst_arr,
    float* __restrict__ denom,
    float* __restrict__ out)
{
    int eid = blockIdx.x * blockDim.x + threadIdx.x;
    if (eid >= N_EDGES) return;

    int s = src[eid];
    int d = dst[eid];

    float2 ev = ((const float2*)e)[eid];
    float ex0 = ev.x * W_edge[0] + ev.y * W_edge[1];
    float ex1 = ev.x * W_edge[2] + ev.y * W_edge[3];

    float a = a_src_arr[s] + a_dst_arr[d]
            + ex0 * W_attn[2 * OUT_DIM] + ex1 * W_attn[2 * OUT_DIM + 1];
    float ea = (a > 0.f) ? a : 0.01f * a;
    float w  = __expf(ea);

    unsafeAtomicAdd(denom + d, w);

    const float4* __restrict__ zrow = (const float4*)(z + (size_t)s * OUT_DIM);
    float4 z0 = zrow[0], z1 = zrow[1], z2 = zrow[2], z3 = zrow[3];

    float* __restrict__ orow = out + (size_t)d * OUT_DIM;
    float zs[OUT_DIM] = { z0.x, z0.y, z0.z, z0.w,
                          z1.x, z1.y, z1.z, z1.w,
                          z2.x, z2.y, z2.z, z2.w,
                          z3.x, z3.y, z3.z, z3.w };
#pragma unroll
    for (int j = 0; j < OUT_DIM; ++j) {
        float ez = ex0 * W_e2n[2 * j] + ex1 * W_e2n[2 * j + 1];
        unsafeAtomicAdd(orow + j, w * (zs[j] + ez));
    }
}

__global__ __launch_bounds__(256) void normalize_kernel(
    float* __restrict__ out, const float* __restrict__ denom)
{
    int tid = blockIdx.x * blockDim.x + threadIdx.x;
    const int total = N_NODES * OUT_DIM / 4;
    if (tid >= total) return;
    int n = tid >> 2;
    float dn = denom[n];
    float inv = (dn != 0.f) ? (1.f / dn) : 0.f;
    float4 v = ((float4*)out)[tid];
    v.x *= inv; v.y *= inv; v.z *= inv; v.w *= inv;
    ((float4*)out)[tid] = v;
}

extern "C" void kernel_launch(void* const* d_in, const int* in_sizes, int n_in,
                              void* d_out, int out_size, void* d_ws, size_t ws_size,
                              hipStream_t stream)
{
    const float* h      = (const float*)d_in[0];
    const float* e      = (const float*)d_in[1];
    const int*   src    = (const int*)  d_in[2];
    const int*   dst    = (const int*)  d_in[3];
    const float* W_fc   = (const float*)d_in[4];
    const float* W_attn = (const float*)d_in[5];
    const float* W_edge = (const float*)d_in[6];
    const float* W_e2n  = (const float*)d_in[7];
    float* out = (float*)d_out;

    // ---- workspace layout (~59 MB, same prefix shape as round 10) ----
    char* ws = (char*)d_ws;
    size_t off = 0;
    float* z          = (float*)(ws + off); off += (size_t)N_NODES * OUT_DIM * 4;  // 6.4 MB (fp32 fb / fp16 main)
    float* a_src_arr  = (float*)(ws + off); off += (size_t)N_NODES * 4;
    float* a_dst_arr  = (float*)(ws + off); off += (size_t)N_NODES * 4;
    float* denom      = (float*)(ws + off); off += (size_t)N_NODES * 4;            // fallback only
    int*   cnt8b      = (int*)  (ws + off); off += (size_t)NSEG * 4;
    int*   bases8     = (int*)  (ws + off); off += (size_t)(NSEG + 4) * 4;         // +sentinel
    int*   cursor8    = (int*)  (ws + off); off += (size_t)NSEG * 4;
    float4* records   = (float4*)(ws + off); off += (size_t)N_EDGES * 16;           // 51.2 MB
    const size_t need = off;

    if (ws_size >= need) {
        __half* zh = (__half*)z;

        zero_seg_kernel<<<(NSEG + 255) / 256, 256, 0, stream>>>(cnt8b);

        fused_proj_count_kernel<<<NPB + NEB, 1024, 0, stream>>>(
            h, W_fc, W_attn, dst, zh, a_src_arr, a_dst_arr, cnt8b);

        scan_seg_kernel<<<1, 256, 0, stream>>>(cnt8b, bases8, cursor8);

        append_kernel<<<NEB, 1024, 0, stream>>>(
            e, src, dst, W_attn, W_edge, a_src_arr, a_dst_arr, cursor8, records);

        bucket_gather_kernel<<<NBUCK, 1024, 0, stream>>>(
            bases8, records, zh, W_e2n, out);
    } else {
        // -------- round-1 atomic fallback (needs ~8 MB) --------
        node_proj_fb_kernel<<<(N_NODES + 255) / 256, 256, 0, stream>>>(
            h, W_fc, W_attn, z, a_src_arr, a_dst_arr, denom, out);

        edge_kernel<<<(N_EDGES + 255) / 256, 256, 0, stream>>>(
            e, src, dst, W_attn, W_edge, W_e2n, z, a_src_arr, a_dst_arr, denom, out);

        normalize_kernel<<<(N_NODES * OUT_DIM / 4 + 255) / 256, 256, 0, stream>>>(
            out, denom);
    }
}

// Round 12
// 280.938 us; speedup vs baseline: 10.2842x; 1.1952x over previous
//
#include <hip/hip_runtime.h>
#include <hip/hip_fp16.h>

#define N_NODES 100000
#define N_EDGES 3200000
#define IN_DIM  62
#define OUT_DIM 16
#define EB_CHUNK 8192                            // edges per count/append block
#define NEB    ((N_EDGES + EB_CHUNK - 1) / EB_CHUNK)   // 391 edge blocks
#define NPB    ((N_NODES + 1023) / 1024)         // 98 node-proj blocks (1024 thr)
#define NBUCK  ((N_NODES + 63) / 64)             // 1563 buckets (dst>>6)
#define NSEG   (NBUCK * 8)                       // 12504 (bucket,class) segments
#define CAP    4096                              // records/bucket LDS cap (avg 2048)

typedef int nat_i2 __attribute__((ext_vector_type(2)));   // builtin-legal int2

// ---------------- K0: zero the (bucket,class) counters ----------------
__global__ __launch_bounds__(256) void zero_seg_kernel(int* __restrict__ cnt8b)
{
    int i = blockIdx.x * blockDim.x + threadIdx.x;
    if (i < NSEG) cnt8b[i] = 0;
}

// ---------------- K1: fused node projection (fp16 z) + bucket count ------
__global__ __launch_bounds__(1024) void fused_proj_count_kernel(
    const float* __restrict__ h,
    const float* __restrict__ W_fc,
    const float* __restrict__ W_attn,
    const int*   __restrict__ dst,
    __half* __restrict__ zh,
    float* __restrict__ a_src_arr,
    float* __restrict__ a_dst_arr,
    int*   __restrict__ cnt8b)
{
    __shared__ int cnt[NBUCK];                   // 6.25 KB

    if (blockIdx.x < NPB) {
        int i = blockIdx.x * 1024 + threadIdx.x;
        if (i >= N_NODES) return;

        float acc[OUT_DIM];
#pragma unroll
        for (int j = 0; j < OUT_DIM; ++j) acc[j] = 0.f;

        const float2* __restrict__ hr = (const float2*)(h + (size_t)i * IN_DIM);
#pragma unroll
        for (int kk = 0; kk < IN_DIM / 2; ++kk) {
            float2 hv = hr[kk];
#pragma unroll
            for (int j = 0; j < OUT_DIM; ++j) {
                acc[j] += hv.x * W_fc[j * IN_DIM + 2 * kk]
                        + hv.y * W_fc[j * IN_DIM + 2 * kk + 1];
            }
        }

        float asrc = 0.f, adst = 0.f;
#pragma unroll
        for (int j = 0; j < OUT_DIM; ++j) {
            asrc += acc[j] * W_attn[j];
            adst += acc[j] * W_attn[OUT_DIM + j];
        }

        union { __half hx[16]; uint4 q[2]; } u;
#pragma unroll
        for (int j = 0; j < OUT_DIM; ++j) u.hx[j] = __float2half(acc[j]);
        uint4* __restrict__ zrow = (uint4*)(zh + (size_t)i * OUT_DIM);
        zrow[0] = u.q[0];
        zrow[1] = u.q[1];

        a_src_arr[i] = asrc;
        a_dst_arr[i] = adst;
    } else {
        int be  = blockIdx.x - NPB;              // edge-chunk index (must match K3)
        int cls = be & 7;
        int tid = threadIdx.x;
        long ebase = (long)be * EB_CHUNK;

        for (int t = tid; t < NBUCK; t += 1024) cnt[t] = 0;
        __syncthreads();

        for (int j = 0; j < EB_CHUNK / 1024; ++j) {
            long eid = ebase + j * 1024 + tid;
            if (eid < N_EDGES) atomicAdd(&cnt[dst[eid] >> 6], 1);
        }
        __syncthreads();

        for (int t = tid; t < NBUCK; t += 1024) {
            int v = cnt[t];
            if (v) atomicAdd(&cnt8b[t * 8 + cls], v);
        }
    }
}

// ---------------- K2: exclusive scan of 12504 segment counts (1 block) ----
__global__ __launch_bounds__(256) void scan_seg_kernel(
    const int* __restrict__ cnt8b,
    int* __restrict__ bases8,
    int* __restrict__ cursor8)
{
    __shared__ int sums[256];
    int tid = threadIdx.x;
    const int PER = (NSEG + 255) / 256;          // 49

    int s = 0;
    for (int k = 0; k < PER; ++k) {
        int i = tid * PER + k;
        if (i < NSEG) s += cnt8b[i];
    }
    sums[tid] = s;
    __syncthreads();
    for (int off = 1; off < 256; off <<= 1) {
        int t = (tid >= off) ? sums[tid - off] : 0;
        __syncthreads();
        sums[tid] += t;
        __syncthreads();
    }
    int run = sums[tid] - s;                     // exclusive base for this chunk
    for (int k = 0; k < PER; ++k) {
        int i = tid * PER + k;
        if (i < NSEG) {
            int v = cnt8b[i];
            bases8[i]  = run;
            cursor8[i] = run;
            run += v;
        }
    }
    if (tid == 0) bases8[NSEG] = N_EDGES;        // sentinel
}

// ---------------- K3: append — coalesced reads, payload staged in LDS -----
// B1: stream inputs in p-order (fully coalesced), compute 8B payload, place
// at sorted LDS slot. B2: stream LDS -> global in sorted order (merged lines).
// NO random global reads anywhere.
__global__ __launch_bounds__(1024) void append_kernel(
    const float* __restrict__ e,
    const int*   __restrict__ src,
    const int*   __restrict__ dst,
    int*         __restrict__ cursor8,
    nat_i2*      __restrict__ records)
{
    __shared__ int  cnt[NBUCK];                  // counts -> rank counters
    __shared__ int  pfx[NBUCK];                  // block-local exclusive prefix
    __shared__ int  combo[NBUCK];                // global_base - pfx
    __shared__ int2 pay[EB_CHUNK];               // 64 KB payload at sorted slot
    __shared__ int  gpos[EB_CHUNK];              // 32 KB global position (scan scratch)

    int be  = blockIdx.x;                        // same chunking/class as K1
    int cls = be & 7;
    int tid = threadIdx.x;
    long ebase = (long)be * EB_CHUNK;
    int chunk_n = (int)min((long)EB_CHUNK, (long)N_EDGES - ebase);

    for (int t = tid; t < NBUCK; t += 1024) cnt[t] = 0;
    __syncthreads();

    // sweep A: count (coalesced dst reads)
    for (int p = tid; p < chunk_n; p += 1024)
        atomicAdd(&cnt[dst[ebase + p] >> 6], 1);
    __syncthreads();

    // block-wide exclusive scan of cnt[NBUCK] (2 elems/thread; gpos as scratch)
    int b0 = 2 * tid, b1 = 2 * tid + 1;
    int c0 = (b0 < NBUCK) ? cnt[b0] : 0;
    int c1 = (b1 < NBUCK) ? cnt[b1] : 0;
    int ts = c0 + c1;
    gpos[tid] = ts;
    __syncthreads();
    for (int off = 1; off < 1024; off <<= 1) {
        int t = (tid >= off) ? gpos[tid - off] : 0;
        __syncthreads();
        gpos[tid] += t;
        __syncthreads();
    }
    int texcl = gpos[tid] - ts;
    if (b0 < NBUCK) pfx[b0] = texcl;
    if (b1 < NBUCK) pfx[b1] = texcl + c0;
    __syncthreads();

    // allocate global group per touched bucket; zero rank counters
    for (int t = tid; t < NBUCK; t += 1024) {
        int v = cnt[t];
        if (v) {
            int gbase = atomicAdd(&cursor8[t * 8 + cls], v);
            combo[t] = gbase - pfx[t];
        }
        cnt[t] = 0;
    }
    __syncthreads();

    // sweep B1: coalesced input stream -> payload at sorted LDS slot
    for (int p = tid; p < chunk_n; p += 1024) {
        long eid = ebase + p;
        int d = dst[eid];
        int b = d >> 6;
        int s = src[eid];
        float2 ev = ((const float2*)e)[eid];

        union { __half2 h2; int i; } u;
        u.h2.x = __float2half(ev.x);
        u.h2.y = __float2half(ev.y);

        int r = atomicAdd(&cnt[b], 1);
        int q = pfx[b] + r;
        pay[q]  = make_int2(u.i, s | ((d & 63) << 17));
        gpos[q] = combo[b] + q;                  // == global_base + rank
    }
    __syncthreads();

    // sweep B2: LDS -> global, sorted order (merged-line nt stores)
    for (int p = tid; p < chunk_n; p += 1024) {
        int2 v = pay[p];
        nat_i2 vv; vv.x = v.x; vv.y = v.y;
        __builtin_nontemporal_store(vv, records + gpos[p]);
    }
}

// ---------------- K4: fused per-bucket bucketize + gather (recompute w) ---
__global__ __launch_bounds__(1024) void bucket_gather_kernel(
    const int*    __restrict__ bases8,
    const nat_i2* __restrict__ records,
    const __half* __restrict__ zh,
    const float*  __restrict__ a_src_arr,
    const float*  __restrict__ a_dst_arr,
    const float*  __restrict__ W_attn,
    const float*  __restrict__ W_edge,
    const float*  __restrict__ W_e2n,
    float* __restrict__ out)
{
    __shared__ int2 rec[CAP];                    // 32 KB
    __shared__ unsigned short inv[CAP];          // 8 KB
    __shared__ int hist[64], pfx[64], cur[64];

    int b   = blockIdx.x;
    int tid = threadIdx.x;
    int lo  = bases8[b * 8];
    int hi  = bases8[b * 8 + 8];                 // sentinel covers b = NBUCK-1
    int n   = hi - lo;

    if (tid < 64) { hist[tid] = 0; cur[tid] = 0; }
    __syncthreads();

    int nl = (n <= CAP) ? n : CAP;               // overflow far beyond 22 sigma

    for (int k = tid; k < nl; k += 1024) {
        nat_i2 r = __builtin_nontemporal_load(records + lo + k);
        rec[k] = make_int2(r.x, r.y);
        atomicAdd(&hist[(r.y >> 17) & 63], 1);
    }
    __syncthreads();

    if (tid < 64) pfx[tid] = hist[tid];
    __syncthreads();
    for (int off = 1; off < 64; off <<= 1) {
        int t = 0;
        if (tid < 64 && tid >= off) t = pfx[tid - off];
        __syncthreads();
        if (tid < 64) pfx[tid] += t;
        __syncthreads();
    }
    if (tid < 64) pfx[tid] -= hist[tid];         // exclusive
    __syncthreads();

    for (int k = tid; k < nl; k += 1024) {
        int ld = (rec[k].y >> 17) & 63;
        int r  = atomicAdd(&cur[ld], 1);
        inv[pfx[ld] + r] = (unsigned short)k;
    }
    __syncthreads();

    // gather: group = node, 16 lanes = features; w recomputed per edge
    int ld   = tid >> 4;
    int lane = tid & 15;
    int node = (b << 6) + ld;
    if (node >= N_NODES) return;

    int m    = hist[ld];
    int base = pfx[ld];

    float we00 = W_edge[0], we01 = W_edge[1], we10 = W_edge[2], we11 = W_edge[3];
    float wa0  = W_attn[2 * OUT_DIM], wa1 = W_attn[2 * OUT_DIM + 1];
    float adst = a_dst_arr[node];

    float acc0 = 0.f, accw0 = 0.f, accx00 = 0.f, accx10 = 0.f;
    float acc1 = 0.f, accw1 = 0.f, accx01 = 0.f, accx11 = 0.f;

    int i = 0;
    for (; i + 1 < m; i += 2) {
        int2 r0 = rec[inv[base + i]];
        int2 r1 = rec[inv[base + i + 1]];
        int s0 = r0.y & 0x1FFFF;
        int s1 = r1.y & 0x1FFFF;

        union { int i; __half2 h2; } u0, u1;
        u0.i = r0.x;  u1.i = r1.x;
        float e00 = __low2float(u0.h2), e01 = __high2float(u0.h2);
        float e10 = __low2float(u1.h2), e11 = __high2float(u1.h2);

        float ex00 = e00 * we00 + e01 * we01, ex10 = e00 * we10 + e01 * we11;
        float ex01 = e10 * we00 + e11 * we01, ex11 = e10 * we10 + e11 * we11;

        float a0 = a_src_arr[s0] + adst + ex00 * wa0 + ex10 * wa1;
        float a1 = a_src_arr[s1] + adst + ex01 * wa0 + ex11 * wa1;
        float ea0 = (a0 > 0.f) ? a0 : 0.01f * a0;
        float ea1 = (a1 > 0.f) ? a1 : 0.01f * a1;
        float w0 = __expf(ea0), w1 = __expf(ea1);

        float zv0 = __half2float(zh[s0 * OUT_DIM + lane]);
        float zv1 = __half2float(zh[s1 * OUT_DIM + lane]);

        acc0   += w0 * zv0;      acc1   += w1 * zv1;
        accw0  += w0;            accw1  += w1;
        accx00 += w0 * ex00;     accx01 += w1 * ex01;
        accx10 += w0 * ex10;     accx11 += w1 * ex11;
    }
    if (i < m) {
        int2 r0 = rec[inv[base + i]];
        int s0 = r0.y & 0x1FFFF;
        union { int i; __half2 h2; } u0;
        u0.i = r0.x;
        float e00 = __low2float(u0.h2), e01 = __high2float(u0.h2);
        float ex00 = e00 * we00 + e01 * we01, ex10 = e00 * we10 + e01 * we11;
        float a0 = a_src_arr[s0] + adst + ex00 * wa0 + ex10 * wa1;
        float ea0 = (a0 > 0.f) ? a0 : 0.01f * a0;
        float w0 = __expf(ea0);
        float zv0 = __half2float(zh[s0 * OUT_DIM + lane]);
        acc0 += w0 * zv0;  accw0 += w0;  accx00 += w0 * ex00;  accx10 += w0 * ex10;
    }

    float acc   = acc0 + acc1;
    float accw  = accw0 + accw1;
    float accx0 = accx00 + accx01;
    float accx1 = accx10 + accx11;

    float ez   = accx0 * W_e2n[2 * lane] + accx1 * W_e2n[2 * lane + 1];
    float invw = (accw != 0.f) ? (1.f / accw) : 0.f;
    out[(size_t)node * OUT_DIM + lane] = (acc + ez) * invw;
}

// ================= Fallback atomic path (round-1, known-passing) ==========

__global__ __launch_bounds__(256) void node_proj_fb_kernel(
    const float* __restrict__ h,
    const float* __restrict__ W_fc,
    const float* __restrict__ W_attn,
    float* __restrict__ z,
    float* __restrict__ a_src_arr,
    float* __restrict__ a_dst_arr,
    float* __restrict__ denom,
    float* __restrict__ out)
{
    int i = blockIdx.x * blockDim.x + threadIdx.x;
    if (i >= N_NODES) return;

    float acc[OUT_DIM];
#pragma unroll
    for (int j = 0; j < OUT_DIM; ++j) acc[j] = 0.f;

    const float2* __restrict__ hr = (const float2*)(h + (size_t)i * IN_DIM);
#pragma unroll
    for (int kk = 0; kk < IN_DIM / 2; ++kk) {
        float2 hv = hr[kk];
#pragma unroll
        for (int j = 0; j < OUT_DIM; ++j) {
            acc[j] += hv.x * W_fc[j * IN_DIM + 2 * kk]
                    + hv.y * W_fc[j * IN_DIM + 2 * kk + 1];
        }
    }

    float asrc = 0.f, adst = 0.f;
#pragma unroll
    for (int j = 0; j < OUT_DIM; ++j) {
        asrc += acc[j] * W_attn[j];
        adst += acc[j] * W_attn[OUT_DIM + j];
    }

    float4* __restrict__ zrow = (float4*)(z + (size_t)i * OUT_DIM);
    zrow[0] = make_float4(acc[0],  acc[1],  acc[2],  acc[3]);
    zrow[1] = make_float4(acc[4],  acc[5],  acc[6],  acc[7]);
    zrow[2] = make_float4(acc[8],  acc[9],  acc[10], acc[11]);
    zrow[3] = make_float4(acc[12], acc[13], acc[14], acc[15]);

    a_src_arr[i] = asrc;
    a_dst_arr[i] = adst;
    denom[i] = 0.f;

    float4 z4 = make_float4(0.f, 0.f, 0.f, 0.f);
    float4* __restrict__ orow = (float4*)(out + (size_t)i * OUT_DIM);
    orow[0] = z4; orow[1] = z4; orow[2] = z4; orow[3] = z4;
}

__global__ __launch_bounds__(256) void edge_kernel(
    const float* __restrict__ e,
    const int*   __restrict__ src,
    const int*   __restrict__ dst,
    const float* __restrict__ W_attn,
    const float* __restrict__ W_edge,
    const float* __restrict__ W_e2n,
    const float* __restrict__ z,
    const float* __restrict__ a_src_arr,
    const float* __restrict__ a_dst_arr,
    float* __restrict__ denom,
    float* __restrict__ out)
{
    int eid = blockIdx.x * blockDim.x + threadIdx.x;
    if (eid >= N_EDGES) return;

    int s = src[eid];
    int d = dst[eid];

    float2 ev = ((const float2*)e)[eid];
    float ex0 = ev.x * W_edge[0] + ev.y * W_edge[1];
    float ex1 = ev.x * W_edge[2] + ev.y * W_edge[3];

    float a = a_src_arr[s] + a_dst_arr[d]
            + ex0 * W_attn[2 * OUT_DIM] + ex1 * W_attn[2 * OUT_DIM + 1];
    float ea = (a > 0.f) ? a : 0.01f * a;
    float w  = __expf(ea);

    unsafeAtomicAdd(denom + d, w);

    const float4* __restrict__ zrow = (const float4*)(z + (size_t)s * OUT_DIM);
    float4 z0 = zrow[0], z1 = zrow[1], z2 = zrow[2], z3 = zrow[3];

    float* __restrict__ orow = out + (size_t)d * OUT_DIM;
    float zs[OUT_DIM] = { z0.x, z0.y, z0.z, z0.w,
                          z1.x, z1.y, z1.z, z1.w,
                          z2.x, z2.y, z2.z, z2.w,
                          z3.x, z3.y, z3.z, z3.w };
#pragma unroll
    for (int j = 0; j < OUT_DIM; ++j) {
        float ez = ex0 * W_e2n[2 * j] + ex1 * W_e2n[2 * j + 1];
        unsafeAtomicAdd(orow + j, w * (zs[j] + ez));
    }
}

__global__ __launch_bounds__(256) void normalize_kernel(
    float* __restrict__ out, const float* __restrict__ denom)
{
    int tid = blockIdx.x * blockDim.x + threadIdx.x;
    const int total = N_NODES * OUT_DIM / 4;
    if (tid >= total) return;
    int n = tid >> 2;
    float dn = denom[n];
    float inv = (dn != 0.f) ? (1.f / dn) : 0.f;
    float4 v = ((float4*)out)[tid];
    v.x *= inv; v.y *= inv; v.z *= inv; v.w *= inv;
    ((float4*)out)[tid] = v;
}

extern "C" void kernel_launch(void* const* d_in, const int* in_sizes, int n_in,
                              void* d_out, int out_size, void* d_ws, size_t ws_size,
                              hipStream_t stream)
{
    const float* h      = (const float*)d_in[0];
    const float* e      = (const float*)d_in[1];
    const int*   src    = (const int*)  d_in[2];
    const int*   dst    = (const int*)  d_in[3];
    const float* W_fc   = (const float*)d_in[4];
    const float* W_attn = (const float*)d_in[5];
    const float* W_edge = (const float*)d_in[6];
    const float* W_e2n  = (const float*)d_in[7];
    float* out = (float*)d_out;

    // ---- workspace layout (~34 MB) ----
    char* ws = (char*)d_ws;
    size_t off = 0;
    float* z          = (float*)(ws + off); off += (size_t)N_NODES * OUT_DIM * 4;  // 6.4 MB (fp32 fb / fp16 main)
    float* a_src_arr  = (float*)(ws + off); off += (size_t)N_NODES * 4;
    float* a_dst_arr  = (float*)(ws + off); off += (size_t)N_NODES * 4;
    float* denom      = (float*)(ws + off); off += (size_t)N_NODES * 4;            // fallback only
    int*   cnt8b      = (int*)  (ws + off); off += (size_t)NSEG * 4;
    int*   bases8     = (int*)  (ws + off); off += (size_t)(NSEG + 4) * 4;         // +sentinel
    int*   cursor8    = (int*)  (ws + off); off += (size_t)NSEG * 4;
    nat_i2* records   = (nat_i2*)(ws + off); off += (size_t)N_EDGES * 8;            // 25.6 MB
    const size_t need = off;

    if (ws_size >= need) {
        __half* zh = (__half*)z;

        zero_seg_kernel<<<(NSEG + 255) / 256, 256, 0, stream>>>(cnt8b);

        fused_proj_count_kernel<<<NPB + NEB, 1024, 0, stream>>>(
            h, W_fc, W_attn, dst, zh, a_src_arr, a_dst_arr, cnt8b);

        scan_seg_kernel<<<1, 256, 0, stream>>>(cnt8b, bases8, cursor8);

        append_kernel<<<NEB, 1024, 0, stream>>>(
            e, src, dst, cursor8, records);

        bucket_gather_kernel<<<NBUCK, 1024, 0, stream>>>(
            bases8, records, zh, a_src_arr, a_dst_arr,
            W_attn, W_edge, W_e2n, out);
    } else {
        // -------- round-1 atomic fallback (needs ~8 MB) --------
        node_proj_fb_kernel<<<(N_NODES + 255) / 256, 256, 0, stream>>>(
            h, W_fc, W_attn, z, a_src_arr, a_dst_arr, denom, out);

        edge_kernel<<<(N_EDGES + 255) / 256, 256, 0, stream>>>(
            e, src, dst, W_attn, W_edge, W_e2n, z, a_src_arr, a_dst_arr, denom, out);

        normalize_kernel<<<(N_NODES * OUT_DIM / 4 + 255) / 256, 256, 0, stream>>>(
            out, denom);
    }
}